// Round 5
// baseline (1660.955 us; speedup 1.0000x reference)
//
#include <hip/hip_runtime.h>
#include <hip/hip_bf16.h>
#include <math.h>

#define N_NODES 10000
#define FEAT    256
#define NEDGE   320000
#define NLAYERS 5
#define NOC     128

// padded tiling for final GEMM: 79 tiles of 128 -> 10112 rows
#define NTILE   79
#define PADROWS 10112
// packed bf16 fragment array: (10112/16) row-tiles * 4 k-steps * 64 lanes * 8 bf16
#define PACKSZ  1294336

typedef __attribute__((ext_vector_type(8))) short bf16x8;
typedef __attribute__((ext_vector_type(4))) float f32x4;

// ---------------- init: deg=1 (self loop), counters=0, attmax=0 ----------------
__global__ void k_init(float* deg, int* cnt, int* fill, int* attm) {
    int i = blockIdx.x * blockDim.x + threadIdx.x;
    if (i < N_NODES) { deg[i] = 1.0f; cnt[i] = 0; fill[i] = 0; }
    if (i < NLAYERS) attm[i] = 0;
}

// ---------------- degree + per-dst edge count ----------------
__global__ void k_count(const int* __restrict__ edges, const float* __restrict__ ew,
                        float* deg, int* cnt) {
    int e = blockIdx.x * blockDim.x + threadIdx.x;
    if (e >= NEDGE) return;
    int d = edges[NEDGE + e];
    atomicAdd(&deg[d], ew[e]);
    atomicAdd(&cnt[d], 1);
}

// ---------------- dinv = rsqrt(deg) in place ----------------
__global__ void k_dinv(float* deg) {
    int i = blockIdx.x * blockDim.x + threadIdx.x;
    if (i < N_NODES) {
        float dg = deg[i];
        deg[i] = (dg > 0.f) ? 1.0f / sqrtf(dg) : 0.f;
    }
}

// ---------------- single-block exclusive scan (10000 entries) ----------------
__global__ void k_scan(const int* __restrict__ cnt, int* __restrict__ ptr) {
    __shared__ int sm[1024];
    __shared__ int carry;
    int t = threadIdx.x;
    if (t == 0) carry = 0;
    __syncthreads();
    for (int base = 0; base < N_NODES; base += 1024) {
        int i = base + t;
        int v = (i < N_NODES) ? cnt[i] : 0;
        sm[t] = v;
        __syncthreads();
        for (int off = 1; off < 1024; off <<= 1) {
            int add = (t >= off) ? sm[t - off] : 0;
            __syncthreads();
            sm[t] += add;
            __syncthreads();
        }
        if (i < N_NODES) ptr[i] = carry + sm[t] - v;   // exclusive
        __syncthreads();
        if (t == 1023) carry += sm[1023];
        __syncthreads();
    }
    if (t == 0) ptr[N_NODES] = carry;
}

// ---------------- CSR fill: col + normalized coefficient ----------------
__global__ void k_fill(const int* __restrict__ edges, const float* __restrict__ ew,
                       const float* __restrict__ dinv, const int* __restrict__ ptr,
                       int* fill, int* __restrict__ col, float* __restrict__ val) {
    int e = blockIdx.x * blockDim.x + threadIdx.x;
    if (e >= NEDGE) return;
    int s = edges[e], d = edges[NEDGE + e];
    int pos = ptr[d] + atomicAdd(&fill[d], 1);
    col[pos] = s;
    val[pos] = dinv[s] * ew[e] * dinv[d];
}

// ---------------- SpMM gather: t[row] = dinv[row]^2*x[row] + sum c_e * x[col_e]
// one wave (64 lanes) per row, float4 per lane covers 256 feats
__global__ __launch_bounds__(256) void k_spmm(const float* __restrict__ x,
        const int* __restrict__ ptr, const int* __restrict__ col,
        const float* __restrict__ val, const float* __restrict__ dinv,
        float* __restrict__ t) {
    int wave = threadIdx.x >> 6;
    int lane = threadIdx.x & 63;
    int row = blockIdx.x * 4 + wave;
    if (row >= N_NODES) return;
    float di = dinv[row];
    float selfc = di * di;
    float4 xv = ((const float4*)(x + (size_t)row * FEAT))[lane];
    float4 acc;
    acc.x = selfc * xv.x; acc.y = selfc * xv.y; acc.z = selfc * xv.z; acc.w = selfc * xv.w;
    int e0 = ptr[row], e1 = ptr[row + 1];
    for (int e = e0; e < e1; ++e) {
        int c = col[e];
        float cv = val[e];
        float4 v = ((const float4*)(x + (size_t)c * FEAT))[lane];
        acc.x += cv * v.x; acc.y += cv * v.y; acc.z += cv * v.z; acc.w += cv * v.w;
    }
    ((float4*)(t + (size_t)row * FEAT))[lane] = acc;
}

// ---------------- tiled fp32 GEMM: C[M,N] = A[M,K]@B[K,N] + bias (+relu+max)
// 64x64 tile, 256 threads, 4x4 per thread. chunked: A[n,k] = feats[(k>>8)*10000+n][k&255]
__global__ __launch_bounds__(256) void k_gemm(const float* __restrict__ A,
        const float* __restrict__ B, const float* __restrict__ bias,
        float* __restrict__ C, int M, int N, int K, int chunked,
        int* attm, int do_relu) {
    __shared__ float As[16][68];
    __shared__ float Bs[16][68];
    int tid = threadIdx.x;
    int tx = tid & 15, ty = tid >> 4;
    int m0 = blockIdx.x * 64, n0 = blockIdx.y * 64;
    float acc[4][4];
#pragma unroll
    for (int i = 0; i < 4; ++i)
#pragma unroll
        for (int j = 0; j < 4; ++j) acc[i][j] = 0.f;

    int arow = m0 + (tid >> 2); if (arow >= M) arow = M - 1;
    int am = tid >> 2;
    int akk = (tid & 3) * 4;
    int bk = tid >> 4;
    int bn = (tid & 15) * 4;

    for (int k0 = 0; k0 < K; k0 += 16) {
        int ka = k0 + akk;
        float4 av;
        if (chunked)
            av = *(const float4*)(A + ((size_t)(ka >> 8) * N_NODES + arow) * FEAT + (ka & 255));
        else
            av = *(const float4*)(A + (size_t)arow * K + ka);
        float4 bv = *(const float4*)(B + (size_t)(k0 + bk) * N + (n0 + bn));
        __syncthreads();
        As[akk + 0][am] = av.x;
        As[akk + 1][am] = av.y;
        As[akk + 2][am] = av.z;
        As[akk + 3][am] = av.w;
        *(float4*)&Bs[bk][bn] = bv;
        __syncthreads();
#pragma unroll
        for (int kk = 0; kk < 16; ++kk) {
            float4 a4 = *(const float4*)&As[kk][ty * 4];
            float4 b4 = *(const float4*)&Bs[kk][tx * 4];
            float a[4] = {a4.x, a4.y, a4.z, a4.w};
            float b[4] = {b4.x, b4.y, b4.z, b4.w};
#pragma unroll
            for (int i = 0; i < 4; ++i)
#pragma unroll
                for (int j = 0; j < 4; ++j) acc[i][j] += a[i] * b[j];
        }
    }

    float lmax = 0.f;
#pragma unroll
    for (int i = 0; i < 4; ++i) {
        int m = m0 + ty * 4 + i;
        if (m < M) {
            float vals[4];
#pragma unroll
            for (int j = 0; j < 4; ++j) {
                float v = acc[i][j] + bias[n0 + tx * 4 + j];
                if (do_relu) { v = fmaxf(v, 0.f); lmax = fmaxf(lmax, v); }
                vals[j] = v;
            }
            *(float4*)(C + (size_t)m * N + n0 + tx * 4) =
                make_float4(vals[0], vals[1], vals[2], vals[3]);
        }
    }
    if (do_relu) {
        __syncthreads();
        float* red = (float*)As;
        red[tid] = lmax;
        __syncthreads();
        for (int s = 128; s > 0; s >>= 1) {
            if (tid < s) red[tid] = fmaxf(red[tid], red[tid + s]);
            __syncthreads();
        }
        if (tid == 0) atomicMax(attm, __float_as_int(red[0]));  // all values >= 0
    }
}

// ---------------- attention MLP (5 -> 25 relu -> 5 sigmoid), one tiny block ----
__global__ void k_att(const int* __restrict__ attm, const float* __restrict__ fc1w,
                      const float* __restrict__ fc1b, const float* __restrict__ fc2w,
                      const float* __restrict__ fc2b, float* __restrict__ att) {
    __shared__ float a0[NLAYERS], a1[5 * NLAYERS];
    int t = threadIdx.x;
    if (t < NLAYERS) a0[t] = __int_as_float(attm[t]);
    __syncthreads();
    if (t < 5 * NLAYERS) {
        float s = fc1b[t];
        for (int c = 0; c < NLAYERS; ++c) s += fc1w[t * NLAYERS + c] * a0[c];
        a1[t] = fmaxf(s, 0.f);
    }
    __syncthreads();
    if (t < NLAYERS) {
        float s = fc2b[t];
        for (int c = 0; c < 5 * NLAYERS; ++c) s += fc2w[t * 5 * NLAYERS + c] * a1[c];
        att[t] = 1.f / (1.f + expf(-s));
    }
}

// ---------------- B'[k*128+o] = cw[o*1280+k] * att[k>>8] ----------------
__global__ void k_bprime(const float* __restrict__ cw, const float* __restrict__ att,
                         float* __restrict__ bp) {
    int idx = blockIdx.x * blockDim.x + threadIdx.x;
    if (idx >= NLAYERS * FEAT * NOC) return;
    int k = idx >> 7;                       // 0..1279
    int o = idx & (NOC - 1);
    bp[idx] = cw[(size_t)o * (NLAYERS * FEAT) + k] * att[k >> 8];
}

// ---------------- split-bf16 pack for the final MFMA GEMM ---------------------
// src[row][k] fp32 (10000x128) -> hi/lo bf16 in MFMA-fragment-native order:
//   P[(row>>4)*4 + (k>>5)][ ((k>>3)&3)*16 + (row&15) ][ k&7 ]
// so a wave's frag load for (row-tile mt, k-step ks) is base + lane*8: 1KB coalesced.
// rows >= 10000 padded with zeros (PADROWS = 79*128).
__global__ __launch_bounds__(256) void k_pack(const float* __restrict__ src,
        ushort* __restrict__ hi, ushort* __restrict__ lo) {
    int t = blockIdx.x * blockDim.x + threadIdx.x;     // 10112*16 = 161792 threads
    int row = t >> 4;
    int g = t & 15;                                    // which group of 8 k's
    int mt = row >> 4, rr = row & 15;
    int ks = g >> 2, kg = g & 3;
    size_t dst = ((size_t)(mt * 4 + ks) * 64 + kg * 16 + rr) * 8;
    uint h[4] = {0, 0, 0, 0}, l[4] = {0, 0, 0, 0};
    if (row < N_NODES) {
        const float* p = src + (size_t)row * NOC + g * 8;
#pragma unroll
        for (int e = 0; e < 8; ++e) {
            float x = p[e];
            __hip_bfloat16 hb = __float2bfloat16(x);
            float hf = __bfloat162float(hb);
            __hip_bfloat16 lb = __float2bfloat16(x - hf);
            uint hu = *(const ushort*)&hb;
            uint lu = *(const ushort*)&lb;
            h[e >> 1] |= hu << ((e & 1) * 16);
            l[e >> 1] |= lu << ((e & 1) * 16);
        }
    }
    *(uint4*)(hi + dst) = make_uint4(h[0], h[1], h[2], h[3]);
    *(uint4*)(lo + dst) = make_uint4(l[0], l[1], l[2], l[3]);
}

// ---------------- final C[10000,10000] = X @ Y^T via split-bf16 MFMA ----------
// C ~= Xhi Yhi^T + Xhi Ylo^T + Xlo Yhi^T  (lo*lo dropped, ~1e-4 rel err)
// 128x128 tile, 4 waves, each wave one 64x64 sub-tile = 4x4 frags of 16x16x32.
// No LDS, no barriers: operands stream from packed L3-resident arrays.
__global__ __launch_bounds__(256) void k_final_mfma(
        const ushort* __restrict__ xh, const ushort* __restrict__ xl,
        const ushort* __restrict__ yh, const ushort* __restrict__ yl,
        float* __restrict__ C) {
    // bijective XCD swizzle (nwg = 6241 = 8*780 + 1)
    int bid = blockIdx.x;
    const int nwg = NTILE * NTILE;
    const int q = nwg >> 3, r = nwg & 7;
    int xcd = bid & 7, loc = bid >> 3;
    int wg = (xcd < r ? xcd * (q + 1) : r * (q + 1) + (xcd - r) * q) + loc;
    int tm = wg / NTILE, tn = wg % NTILE;

    int tid = threadIdx.x;
    int wave = tid >> 6, lane = tid & 63;
    int m0 = tm * 128 + (wave >> 1) * 64;
    int n0 = tn * 128 + (wave & 1) * 64;
    int mtb = m0 >> 4, ntb = n0 >> 4;

    f32x4 acc[4][4];
#pragma unroll
    for (int i = 0; i < 4; ++i)
#pragma unroll
        for (int j = 0; j < 4; ++j) acc[i][j] = (f32x4){0.f, 0.f, 0.f, 0.f};

#pragma unroll
    for (int ks = 0; ks < 4; ++ks) {
        bf16x8 ah[4], al[4], bh[4], bl[4];
#pragma unroll
        for (int i = 0; i < 4; ++i) {
            size_t ao = ((size_t)((mtb + i) * 4 + ks) * 64 + lane) * 8;
            size_t bo = ((size_t)((ntb + i) * 4 + ks) * 64 + lane) * 8;
            ah[i] = *(const bf16x8*)(xh + ao);
            al[i] = *(const bf16x8*)(xl + ao);
            bh[i] = *(const bf16x8*)(yh + bo);
            bl[i] = *(const bf16x8*)(yl + bo);
        }
#pragma unroll
        for (int i = 0; i < 4; ++i)
#pragma unroll
            for (int j = 0; j < 4; ++j) {
                acc[i][j] = __builtin_amdgcn_mfma_f32_16x16x32_bf16(ah[i], bh[j], acc[i][j], 0, 0, 0);
                acc[i][j] = __builtin_amdgcn_mfma_f32_16x16x32_bf16(ah[i], bl[j], acc[i][j], 0, 0, 0);
                acc[i][j] = __builtin_amdgcn_mfma_f32_16x16x32_bf16(al[i], bh[j], acc[i][j], 0, 0, 0);
            }
    }

    // D frag layout: row = (lane>>4)*4 + reg, col = lane&15
    int rbase = (lane >> 4) * 4, cn = lane & 15;
    bool full = (m0 + 63 < N_NODES) && (n0 + 63 < N_NODES);
    if (full) {
#pragma unroll
        for (int i = 0; i < 4; ++i)
#pragma unroll
            for (int j = 0; j < 4; ++j) {
                size_t base = (size_t)(m0 + i * 16 + rbase) * N_NODES + (n0 + j * 16 + cn);
#pragma unroll
                for (int rr = 0; rr < 4; ++rr)
                    C[base + (size_t)rr * N_NODES] = acc[i][j][rr];
            }
    } else {
        for (int i = 0; i < 4; ++i)
            for (int j = 0; j < 4; ++j) {
                int ccol = n0 + j * 16 + cn;
                if (ccol >= N_NODES) continue;
                for (int rr = 0; rr < 4; ++rr) {
                    int mr = m0 + i * 16 + rbase + rr;
                    if (mr < N_NODES)
                        C[(size_t)mr * N_NODES + ccol] = acc[i][j][rr];
                }
            }
    }
}

extern "C" void kernel_launch(void* const* d_in, const int* in_sizes, int n_in,
                              void* d_out, int out_size, void* d_ws, size_t ws_size,
                              hipStream_t stream) {
    (void)in_sizes; (void)n_in; (void)out_size; (void)ws_size;

    // ---- workspace carve-up (~75.1 MB) ----
    float* ws     = (float*)d_ws;
    float* feats  = ws;                          // 5*10000*256 = 12,800,000
    float* tbuf   = feats + 12800000;            // 2,560,000
    float* outx   = tbuf + 2560000;              // 1,280,000
    float* outy   = outx + 1280000;              // 1,280,000
    float* dinv   = outy + 1280000;              // 10,016 (deg -> dinv in place)
    float* val    = dinv + 10016;                // 320,000
    float* bprime = val + 320000;                // 163,840
    float* attF   = bprime + 163840;             // 16
    int*   ptr    = (int*)(attF + 16);           // 10,016
    int*   cnt    = ptr + 10016;                 // 10,016
    int*   fill   = cnt + 10016;                 // 10,016
    int*   col    = fill + 10016;                // 320,000
    int*   attm   = col + 320000;                // 16

    // packed split-bf16 operands for the final GEMM alias the feats region
    // (feats is dead after the last branch-out GEMM). 4 * 1,294,336 ushort = 10.35 MB.
    ushort* pxh = (ushort*)feats;
    ushort* pxl = pxh + PACKSZ;
    ushort* pyh = pxl + PACKSZ;
    ushort* pyl = pyh + PACKSZ;

    for (int b = 0; b < 2; ++b) {
        const float* x0   = (const float*)d_in[b == 0 ? 0 : 1];
        const float* ew   = (const float*)d_in[b == 0 ? 2 : 3];
        const float* W    = (const float*)d_in[b == 0 ? 4 : 6];
        const float* bias = (const float*)d_in[b == 0 ? 5 : 7];
        const float* fc1w = (const float*)d_in[b == 0 ? 8 : 12];
        const float* fc1b = (const float*)d_in[b == 0 ? 9 : 13];
        const float* fc2w = (const float*)d_in[b == 0 ? 10 : 14];
        const float* fc2b = (const float*)d_in[b == 0 ? 11 : 15];
        const float* cw   = (const float*)d_in[b == 0 ? 16 : 18];
        const float* cb   = (const float*)d_in[b == 0 ? 17 : 19];
        const int* edges  = (const int*)d_in[b == 0 ? 20 : 21];
        float* outb = (b == 0) ? outx : outy;

        k_init<<<40, 256, 0, stream>>>(dinv, cnt, fill, attm);
        k_count<<<1250, 256, 0, stream>>>(edges, ew, dinv, cnt);
        k_dinv<<<40, 256, 0, stream>>>(dinv);
        k_scan<<<1, 1024, 0, stream>>>(cnt, ptr);
        k_fill<<<1250, 256, 0, stream>>>(edges, ew, dinv, ptr, fill, col, val);

        for (int l = 0; l < NLAYERS; ++l) {
            const float* prev = (l == 0) ? x0 : (feats + (size_t)(l - 1) * N_NODES * FEAT);
            k_spmm<<<2500, 256, 0, stream>>>(prev, ptr, col, val, dinv, tbuf);
            k_gemm<<<dim3(157, 4), 256, 0, stream>>>(
                tbuf, W + (size_t)l * FEAT * FEAT, bias + (size_t)l * FEAT,
                feats + (size_t)l * N_NODES * FEAT,
                N_NODES, FEAT, FEAT, 0, attm + l, 1);
        }

        k_att<<<1, 64, 0, stream>>>(attm, fc1w, fc1b, fc2w, fc2b, attF);
        k_bprime<<<640, 256, 0, stream>>>(cw, attF, bprime);
        k_gemm<<<dim3(157, 2), 256, 0, stream>>>(
            feats, bprime, cb, outb, N_NODES, NOC, NLAYERS * FEAT, 1, nullptr, 0);
    }

    // pack outx/outy into fragment-native split-bf16 (feats now dead -> aliased)
    k_pack<<<632, 256, 0, stream>>>(outx, pxh, pxl);
    k_pack<<<632, 256, 0, stream>>>(outy, pyh, pyl);
    k_final_mfma<<<NTILE * NTILE, 256, 0, stream>>>(pxh, pxl, pyh, pyl, (float*)d_out);
}

// Round 9
// 1603.403 us; speedup vs baseline: 1.0359x; 1.0359x over previous
//
#include <hip/hip_runtime.h>
#include <hip/hip_bf16.h>
#include <math.h>

#define N_NODES 10000
#define FEAT    256
#define NEDGE   320000
#define NLAYERS 5
#define NOC     128

// padded tiling for final GEMM: 79 tiles of 128 -> 10112 rows
#define NTILE   79
#define PADROWS 10112
// packed f16 fragment array (final GEMM): (10112/16) row-tiles * 4 k-steps * 64 lanes * 8
#define PACKSZ  1294336

typedef __attribute__((ext_vector_type(8))) _Float16 f16x8;
typedef __attribute__((ext_vector_type(4))) float f32x4;

// split x into f16 hi + f16 lo (x ~= hi + lo, residual ~2^-22 rel)
static __device__ inline void f16split(float x, ushort& h, ushort& l) {
    _Float16 hf = (_Float16)x;
    float hb = (float)hf;
    _Float16 lf = (_Float16)(x - hb);
    union { _Float16 f; ushort u; } ch, cl;
    ch.f = hf; cl.f = lf;
    h = ch.u; l = cl.u;
}

// ---------------- init: deg=1 (self loop), counters=0, attmax=0 ----------------
__global__ void k_init(float* deg, int* cnt, int* fill, int* attm) {
    int i = blockIdx.x * blockDim.x + threadIdx.x;
    if (i < N_NODES) { deg[i] = 1.0f; cnt[i] = 0; fill[i] = 0; }
    if (i < NLAYERS) attm[i] = 0;
}

// ---------------- degree + per-dst edge count ----------------
__global__ void k_count(const int* __restrict__ edges, const float* __restrict__ ew,
                        float* deg, int* cnt) {
    int e = blockIdx.x * blockDim.x + threadIdx.x;
    if (e >= NEDGE) return;
    int d = edges[NEDGE + e];
    atomicAdd(&deg[d], ew[e]);
    atomicAdd(&cnt[d], 1);
}

// ---------------- dinv = rsqrt(deg) in place ----------------
__global__ void k_dinv(float* deg) {
    int i = blockIdx.x * blockDim.x + threadIdx.x;
    if (i < N_NODES) {
        float dg = deg[i];
        deg[i] = (dg > 0.f) ? 1.0f / sqrtf(dg) : 0.f;
    }
}

// ---------------- single-block exclusive scan (10000 entries) ----------------
__global__ void k_scan(const int* __restrict__ cnt, int* __restrict__ ptr) {
    __shared__ int sm[1024];
    __shared__ int carry;
    int t = threadIdx.x;
    if (t == 0) carry = 0;
    __syncthreads();
    for (int base = 0; base < N_NODES; base += 1024) {
        int i = base + t;
        int v = (i < N_NODES) ? cnt[i] : 0;
        sm[t] = v;
        __syncthreads();
        for (int off = 1; off < 1024; off <<= 1) {
            int add = (t >= off) ? sm[t - off] : 0;
            __syncthreads();
            sm[t] += add;
            __syncthreads();
        }
        if (i < N_NODES) ptr[i] = carry + sm[t] - v;   // exclusive
        __syncthreads();
        if (t == 1023) carry += sm[1023];
        __syncthreads();
    }
    if (t == 0) ptr[N_NODES] = carry;
}

// ---------------- CSR fill: col + normalized coefficient ----------------
__global__ void k_fill(const int* __restrict__ edges, const float* __restrict__ ew,
                       const float* __restrict__ dinv, const int* __restrict__ ptr,
                       int* fill, int* __restrict__ col, float* __restrict__ val) {
    int e = blockIdx.x * blockDim.x + threadIdx.x;
    if (e >= NEDGE) return;
    int s = edges[e], d = edges[NEDGE + e];
    int pos = ptr[d] + atomicAdd(&fill[d], 1);
    col[pos] = s;
    val[pos] = dinv[s] * ew[e] * dinv[d];
}

// ---------------- SpMM gather: t[row] = dinv[row]^2*x[row] + sum c_e * x[col_e]
// one wave per row; OUTPUT is written as packed f16 hi/lo MFMA A-fragments:
//   lane l holds k = 4l..4l+3; slot = ((mt*8+ks)*64 + kg*16 + rr)*8 + e0
//   (mt=row>>4, rr=row&15, ks=l>>3, kg=(l>>1)&3, e0=(l&1)*4). 10000 = 625*16
//   exactly, so every fragment slot is written - no padding needed.
__global__ __launch_bounds__(256) void k_spmm(const float* __restrict__ x,
        const int* __restrict__ ptr, const int* __restrict__ col,
        const float* __restrict__ val, const float* __restrict__ dinv,
        ushort* __restrict__ th, ushort* __restrict__ tl) {
    int wave = threadIdx.x >> 6;
    int lane = threadIdx.x & 63;
    int row = blockIdx.x * 4 + wave;
    if (row >= N_NODES) return;
    float di = dinv[row];
    float selfc = di * di;
    float4 xv = ((const float4*)(x + (size_t)row * FEAT))[lane];
    float4 acc;
    acc.x = selfc * xv.x; acc.y = selfc * xv.y; acc.z = selfc * xv.z; acc.w = selfc * xv.w;
    int e0 = ptr[row], e1 = ptr[row + 1];
    for (int e = e0; e < e1; ++e) {
        int c = col[e];
        float cv = val[e];
        float4 v = ((const float4*)(x + (size_t)c * FEAT))[lane];
        acc.x += cv * v.x; acc.y += cv * v.y; acc.z += cv * v.z; acc.w += cv * v.w;
    }
    int mt = row >> 4, rr = row & 15;
    int ks = lane >> 3, kg = (lane >> 1) & 3, ee = (lane & 1) * 4;
    size_t pb = ((size_t)(mt * 8 + ks) * 64 + kg * 16 + rr) * 8 + ee;
    ushort h[4], l[4];
    f16split(acc.x, h[0], l[0]); f16split(acc.y, h[1], l[1]);
    f16split(acc.z, h[2], l[2]); f16split(acc.w, h[3], l[3]);
    *(uint2*)(th + pb) = make_uint2((uint)h[0] | ((uint)h[1] << 16),
                                    (uint)h[2] | ((uint)h[3] << 16));
    *(uint2*)(tl + pb) = make_uint2((uint)l[0] | ((uint)l[1] << 16),
                                    (uint)l[2] | ((uint)l[3] << 16));
}

// ---------------- pack W [5][256][256] (W[l][k][n]) -> f16 hi/lo B-fragments ---
// B-frag slot (per layer): ((nt*8+ks)*64 + kg*16 + rc)*8 + e ; n=nt*16+rc, k=ks*32+kg*8+e
__global__ void k_packW(const float* __restrict__ W, ushort* __restrict__ wh,
                        ushort* __restrict__ wl) {
    int g = blockIdx.x * blockDim.x + threadIdx.x;
    if (g >= NLAYERS * 8192) return;
    int l = g >> 13, gl = g & 8191;
    int rc = gl & 15, kg = (gl >> 4) & 3, ks = (gl >> 6) & 7, nt = gl >> 9;
    int n = nt * 16 + rc, k0 = ks * 32 + kg * 8;
    const float* src = W + (size_t)l * 65536 + (size_t)k0 * 256 + n;
    uint hw[4], lw[4];
#pragma unroll
    for (int e = 0; e < 8; e += 2) {
        ushort h0, l0, h1, l1;
        f16split(src[(size_t)e * 256], h0, l0);
        f16split(src[(size_t)(e + 1) * 256], h1, l1);
        hw[e >> 1] = (uint)h0 | ((uint)h1 << 16);
        lw[e >> 1] = (uint)l0 | ((uint)l1 << 16);
    }
    size_t dst = (size_t)g * 8;
    *(uint4*)(wh + dst) = make_uint4(hw[0], hw[1], hw[2], hw[3]);
    *(uint4*)(wl + dst) = make_uint4(lw[0], lw[1], lw[2], lw[3]);
}

// ---------------- layer GEMM via f16-split MFMA --------------------------------
// out[m,n] = relu( sum_k t[m,k] W[k,n] + bias[n] ), m<10000, n<256, K=256
// C ~= ThWh + ThWl + TlWh (lo*lo dropped, ~2^-22 rel: fp32-level).
// 128x128 block tile, 4 waves of 64x64, fused bias+relu+feats-store+max->attm.
__global__ __launch_bounds__(256) void k_gemm_l(
        const ushort* __restrict__ th, const ushort* __restrict__ tl,
        const ushort* __restrict__ wh, const ushort* __restrict__ wl,
        const float* __restrict__ bias, float* __restrict__ out, int* attm) {
    __shared__ float red[256];
    int tid = threadIdx.x;
    int wave = tid >> 6, lane = tid & 63;
    int m0 = blockIdx.x * 128 + (wave >> 1) * 64;
    int n0 = blockIdx.y * 128 + (wave & 1) * 64;
    int mtb = m0 >> 4, ntb = n0 >> 4;

    f32x4 acc[4][4];
#pragma unroll
    for (int i = 0; i < 4; ++i)
#pragma unroll
        for (int j = 0; j < 4; ++j) acc[i][j] = (f32x4){0.f, 0.f, 0.f, 0.f};

#pragma unroll
    for (int ks = 0; ks < 8; ++ks) {
        f16x8 ah[4], al[4], bh[4], bl[4];
#pragma unroll
        for (int i = 0; i < 4; ++i) {
            int mt = mtb + i; if (mt > 624) mt = 624;   // rows>=10000 discarded below
            size_t ao = ((size_t)(mt * 8 + ks) * 64 + lane) * 8;
            size_t bo = ((size_t)((ntb + i) * 8 + ks) * 64 + lane) * 8;
            ah[i] = *(const f16x8*)(th + ao);
            al[i] = *(const f16x8*)(tl + ao);
            bh[i] = *(const f16x8*)(wh + bo);
            bl[i] = *(const f16x8*)(wl + bo);
        }
#pragma unroll
        for (int i = 0; i < 4; ++i)
#pragma unroll
            for (int j = 0; j < 4; ++j) {
                acc[i][j] = __builtin_amdgcn_mfma_f32_16x16x32_f16(ah[i], bh[j], acc[i][j], 0, 0, 0);
                acc[i][j] = __builtin_amdgcn_mfma_f32_16x16x32_f16(ah[i], bl[j], acc[i][j], 0, 0, 0);
                acc[i][j] = __builtin_amdgcn_mfma_f32_16x16x32_f16(al[i], bh[j], acc[i][j], 0, 0, 0);
            }
    }

    // D layout: row=(lane>>4)*4+reg, col=lane&15
    int rbase = (lane >> 4) * 4, cn = lane & 15;
    float lmax = 0.f;
#pragma unroll
    for (int i = 0; i < 4; ++i)
#pragma unroll
        for (int j = 0; j < 4; ++j) {
            int n = n0 + j * 16 + cn;
            float bv = bias[n];
#pragma unroll
            for (int rr = 0; rr < 4; ++rr) {
                int m = m0 + i * 16 + rbase + rr;
                if (m < N_NODES) {
                    float v = fmaxf(acc[i][j][rr] + bv, 0.f);
                    lmax = fmaxf(lmax, v);
                    out[(size_t)m * FEAT + n] = v;
                }
            }
        }
    red[tid] = lmax;
    __syncthreads();
    for (int s = 128; s > 0; s >>= 1) {
        if (tid < s) red[tid] = fmaxf(red[tid], red[tid + s]);
        __syncthreads();
    }
    if (tid == 0) atomicMax(attm, __float_as_int(red[0]));   // all values >= 0
}

// ---------------- tiled fp32 GEMM (branch-out only): C = A@B + bias ------------
// 64x64 tile, 256 threads, 4x4/thread. chunked: A[n,k] = feats[(k>>8)*10000+n][k&255]
__global__ __launch_bounds__(256) void k_gemm(const float* __restrict__ A,
        const float* __restrict__ B, const float* __restrict__ bias,
        float* __restrict__ C, int M, int N, int K, int chunked,
        int* attm, int do_relu) {
    __shared__ float As[16][68];
    __shared__ float Bs[16][68];
    int tid = threadIdx.x;
    int tx = tid & 15, ty = tid >> 4;
    int m0 = blockIdx.x * 64, n0 = blockIdx.y * 64;
    float acc[4][4];
#pragma unroll
    for (int i = 0; i < 4; ++i)
#pragma unroll
        for (int j = 0; j < 4; ++j) acc[i][j] = 0.f;

    int arow = m0 + (tid >> 2); if (arow >= M) arow = M - 1;
    int am = tid >> 2;
    int akk = (tid & 3) * 4;
    int bk = tid >> 4;
    int bn = (tid & 15) * 4;

    for (int k0 = 0; k0 < K; k0 += 16) {
        int ka = k0 + akk;
        float4 av;
        if (chunked)
            av = *(const float4*)(A + ((size_t)(ka >> 8) * N_NODES + arow) * FEAT + (ka & 255));
        else
            av = *(const float4*)(A + (size_t)arow * K + ka);
        float4 bv = *(const float4*)(B + (size_t)(k0 + bk) * N + (n0 + bn));
        __syncthreads();
        As[akk + 0][am] = av.x;
        As[akk + 1][am] = av.y;
        As[akk + 2][am] = av.z;
        As[akk + 3][am] = av.w;
        *(float4*)&Bs[bk][bn] = bv;
        __syncthreads();
#pragma unroll
        for (int kk = 0; kk < 16; ++kk) {
            float4 a4 = *(const float4*)&As[kk][ty * 4];
            float4 b4 = *(const float4*)&Bs[kk][tx * 4];
            float a[4] = {a4.x, a4.y, a4.z, a4.w};
            float b[4] = {b4.x, b4.y, b4.z, b4.w};
#pragma unroll
            for (int i = 0; i < 4; ++i)
#pragma unroll
                for (int j = 0; j < 4; ++j) acc[i][j] += a[i] * b[j];
        }
    }

    float lmax = 0.f;
#pragma unroll
    for (int i = 0; i < 4; ++i) {
        int m = m0 + ty * 4 + i;
        if (m < M) {
            float vals[4];
#pragma unroll
            for (int j = 0; j < 4; ++j) {
                float v = acc[i][j] + bias[n0 + tx * 4 + j];
                if (do_relu) { v = fmaxf(v, 0.f); lmax = fmaxf(lmax, v); }
                vals[j] = v;
            }
            *(float4*)(C + (size_t)m * N + n0 + tx * 4) =
                make_float4(vals[0], vals[1], vals[2], vals[3]);
        }
    }
    if (do_relu) {
        __syncthreads();
        float* red = (float*)As;
        red[tid] = lmax;
        __syncthreads();
        for (int s = 128; s > 0; s >>= 1) {
            if (tid < s) red[tid] = fmaxf(red[tid], red[tid + s]);
            __syncthreads();
        }
        if (tid == 0) atomicMax(attm, __float_as_int(red[0]));
    }
}

// ---------------- attention MLP (5 -> 25 relu -> 5 sigmoid), one tiny block ----
__global__ void k_att(const int* __restrict__ attm, const float* __restrict__ fc1w,
                      const float* __restrict__ fc1b, const float* __restrict__ fc2w,
                      const float* __restrict__ fc2b, float* __restrict__ att) {
    __shared__ float a0[NLAYERS], a1[5 * NLAYERS];
    int t = threadIdx.x;
    if (t < NLAYERS) a0[t] = __int_as_float(attm[t]);
    __syncthreads();
    if (t < 5 * NLAYERS) {
        float s = fc1b[t];
        for (int c = 0; c < NLAYERS; ++c) s += fc1w[t * NLAYERS + c] * a0[c];
        a1[t] = fmaxf(s, 0.f);
    }
    __syncthreads();
    if (t < NLAYERS) {
        float s = fc2b[t];
        for (int c = 0; c < 5 * NLAYERS; ++c) s += fc2w[t * 5 * NLAYERS + c] * a1[c];
        att[t] = 1.f / (1.f + expf(-s));
    }
}

// ---------------- B'[k*128+o] = cw[o*1280+k] * att[k>>8] ----------------
__global__ void k_bprime(const float* __restrict__ cw, const float* __restrict__ att,
                         float* __restrict__ bp) {
    int idx = blockIdx.x * blockDim.x + threadIdx.x;
    if (idx >= NLAYERS * FEAT * NOC) return;
    int k = idx >> 7;                       // 0..1279
    int o = idx & (NOC - 1);
    bp[idx] = cw[(size_t)o * (NLAYERS * FEAT) + k] * att[k >> 8];
}

// ---------------- split-f16 pack for the final MFMA GEMM ----------------------
// src[row][k] fp32 (10000x128) -> hi/lo f16 fragment-native; rows>=10000 zeroed.
__global__ __launch_bounds__(256) void k_pack(const float* __restrict__ src,
        ushort* __restrict__ hi, ushort* __restrict__ lo) {
    int t = blockIdx.x * blockDim.x + threadIdx.x;     // 10112*16 = 161792 threads
    int row = t >> 4;
    int g = t & 15;                                    // which group of 8 k's
    int mt = row >> 4, rr = row & 15;
    int ks = g >> 2, kg = g & 3;
    size_t dst = ((size_t)(mt * 4 + ks) * 64 + kg * 16 + rr) * 8;
    uint h[4] = {0, 0, 0, 0}, l[4] = {0, 0, 0, 0};
    if (row < N_NODES) {
        const float* p = src + (size_t)row * NOC + g * 8;
#pragma unroll
        for (int e = 0; e < 8; ++e) {
            ushort hu, lu;
            f16split(p[e], hu, lu);
            h[e >> 1] |= (uint)hu << ((e & 1) * 16);
            l[e >> 1] |= (uint)lu << ((e & 1) * 16);
        }
    }
    *(uint4*)(hi + dst) = make_uint4(h[0], h[1], h[2], h[3]);
    *(uint4*)(lo + dst) = make_uint4(l[0], l[1], l[2], l[3]);
}

// ---------------- final C[10000,10000] = X @ Y^T via split-f16 MFMA -----------
__global__ __launch_bounds__(256) void k_final_mfma(
        const ushort* __restrict__ xh, const ushort* __restrict__ xl,
        const ushort* __restrict__ yh, const ushort* __restrict__ yl,
        float* __restrict__ C) {
    // bijective XCD swizzle (nwg = 6241 = 8*780 + 1)
    int bid = blockIdx.x;
    const int nwg = NTILE * NTILE;
    const int q = nwg >> 3, r = nwg & 7;
    int xcd = bid & 7, loc = bid >> 3;
    int wg = (xcd < r ? xcd * (q + 1) : r * (q + 1) + (xcd - r) * q) + loc;
    int tm = wg / NTILE, tn = wg % NTILE;

    int tid = threadIdx.x;
    int wave = tid >> 6, lane = tid & 63;
    int m0 = tm * 128 + (wave >> 1) * 64;
    int n0 = tn * 128 + (wave & 1) * 64;
    int mtb = m0 >> 4, ntb = n0 >> 4;

    f32x4 acc[4][4];
#pragma unroll
    for (int i = 0; i < 4; ++i)
#pragma unroll
        for (int j = 0; j < 4; ++j) acc[i][j] = (f32x4){0.f, 0.f, 0.f, 0.f};

#pragma unroll
    for (int ks = 0; ks < 4; ++ks) {
        f16x8 ah[4], al[4], bh[4], bl[4];
#pragma unroll
        for (int i = 0; i < 4; ++i) {
            size_t ao = ((size_t)((mtb + i) * 4 + ks) * 64 + lane) * 8;
            size_t bo = ((size_t)((ntb + i) * 4 + ks) * 64 + lane) * 8;
            ah[i] = *(const f16x8*)(xh + ao);
            al[i] = *(const f16x8*)(xl + ao);
            bh[i] = *(const f16x8*)(yh + bo);
            bl[i] = *(const f16x8*)(yl + bo);
        }
#pragma unroll
        for (int i = 0; i < 4; ++i)
#pragma unroll
            for (int j = 0; j < 4; ++j) {
                acc[i][j] = __builtin_amdgcn_mfma_f32_16x16x32_f16(ah[i], bh[j], acc[i][j], 0, 0, 0);
                acc[i][j] = __builtin_amdgcn_mfma_f32_16x16x32_f16(ah[i], bl[j], acc[i][j], 0, 0, 0);
                acc[i][j] = __builtin_amdgcn_mfma_f32_16x16x32_f16(al[i], bh[j], acc[i][j], 0, 0, 0);
            }
    }

    // D frag layout: row = (lane>>4)*4 + reg, col = lane&15
    int rbase = (lane >> 4) * 4, cn = lane & 15;
    bool full = (m0 + 63 < N_NODES) && (n0 + 63 < N_NODES);
    if (full) {
#pragma unroll
        for (int i = 0; i < 4; ++i)
#pragma unroll
            for (int j = 0; j < 4; ++j) {
                size_t base = (size_t)(m0 + i * 16 + rbase) * N_NODES + (n0 + j * 16 + cn);
#pragma unroll
                for (int rr = 0; rr < 4; ++rr)
                    C[base + (size_t)rr * N_NODES] = acc[i][j][rr];
            }
    } else {
        for (int i = 0; i < 4; ++i)
            for (int j = 0; j < 4; ++j) {
                int ccol = n0 + j * 16 + cn;
                if (ccol >= N_NODES) continue;
                for (int rr = 0; rr < 4; ++rr) {
                    int mr = m0 + i * 16 + rbase + rr;
                    if (mr < N_NODES)
                        C[(size_t)mr * N_NODES + ccol] = acc[i][j][rr];
                }
            }
    }
}

extern "C" void kernel_launch(void* const* d_in, const int* in_sizes, int n_in,
                              void* d_out, int out_size, void* d_ws, size_t ws_size,
                              hipStream_t stream) {
    (void)in_sizes; (void)n_in; (void)out_size; (void)ws_size;

    // ---- workspace carve-up (identical footprint to verified round-5 layout) ----
    float* ws     = (float*)d_ws;
    float* feats  = ws;                          // 5*10000*256 = 12,800,000
    float* tbuf   = feats + 12800000;            // 2,560,000 (now holds th/tl packed)
    float* outx   = tbuf + 2560000;              // 1,280,000
    float* outy   = outx + 1280000;              // 1,280,000
    float* dinv   = outy + 1280000;              // 10,016
    float* val    = dinv + 10016;                // 320,000
    float* bprime = val + 320000;                // 163,840
    float* attF   = bprime + 163840;             // 16
    int*   ptr    = (int*)(attF + 16);           // 10,016
    int*   cnt    = ptr + 10016;                 // 10,016
    int*   fill   = cnt + 10016;                 // 10,016
    int*   col    = fill + 10016;                // 320,000
    int*   attm   = col + 320000;                // 16

    // packed f16 t (A-side, per layer): exactly fills tbuf (2*2.56M ushorts)
    ushort* th = (ushort*)tbuf;
    ushort* tl = th + 2560000;
    // packed f16 W (B-side, 5 layers): aliases outy (outy written only at branch-1
    // end, after the last layer GEMM of branch 1 -> no overlap in lifetime)
    ushort* Wh = (ushort*)outy;
    ushort* Wl = Wh + NLAYERS * 65536;           // 2*327,680 ushorts = 327,680 floats

    // final-GEMM packed operands alias feats (dead after branch-out GEMMs)
    ushort* pxh = (ushort*)feats;
    ushort* pxl = pxh + PACKSZ;
    ushort* pyh = pxl + PACKSZ;
    ushort* pyl = pyh + PACKSZ;

    for (int b = 0; b < 2; ++b) {
        const float* x0   = (const float*)d_in[b == 0 ? 0 : 1];
        const float* ew   = (const float*)d_in[b == 0 ? 2 : 3];
        const float* W    = (const float*)d_in[b == 0 ? 4 : 6];
        const float* bias = (const float*)d_in[b == 0 ? 5 : 7];
        const float* fc1w = (const float*)d_in[b == 0 ? 8 : 12];
        const float* fc1b = (const float*)d_in[b == 0 ? 9 : 13];
        const float* fc2w = (const float*)d_in[b == 0 ? 10 : 14];
        const float* fc2b = (const float*)d_in[b == 0 ? 11 : 15];
        const float* cw   = (const float*)d_in[b == 0 ? 16 : 18];
        const float* cb   = (const float*)d_in[b == 0 ? 17 : 19];
        const int* edges  = (const int*)d_in[b == 0 ? 20 : 21];
        float* outb = (b == 0) ? outx : outy;

        k_init<<<40, 256, 0, stream>>>(dinv, cnt, fill, attm);
        k_count<<<1250, 256, 0, stream>>>(edges, ew, dinv, cnt);
        k_dinv<<<40, 256, 0, stream>>>(dinv);
        k_scan<<<1, 1024, 0, stream>>>(cnt, ptr);
        k_fill<<<1250, 256, 0, stream>>>(edges, ew, dinv, ptr, fill, col, val);
        k_packW<<<160, 256, 0, stream>>>(W, Wh, Wl);

        for (int l = 0; l < NLAYERS; ++l) {
            const float* prev = (l == 0) ? x0 : (feats + (size_t)(l - 1) * N_NODES * FEAT);
            k_spmm<<<2500, 256, 0, stream>>>(prev, ptr, col, val, dinv, th, tl);
            k_gemm_l<<<dim3(79, 2), 256, 0, stream>>>(
                th, tl, Wh + (size_t)l * 65536, Wl + (size_t)l * 65536,
                bias + (size_t)l * FEAT,
                feats + (size_t)l * N_NODES * FEAT, attm + l);
        }

        k_att<<<1, 64, 0, stream>>>(attm, fc1w, fc1b, fc2w, fc2b, attF);
        k_bprime<<<640, 256, 0, stream>>>(cw, attF, bprime);
        k_gemm<<<dim3(157, 2), 256, 0, stream>>>(
            feats, bprime, cb, outb, N_NODES, NOC, NLAYERS * FEAT, 1, nullptr, 0);
    }

    // pack outx/outy into fragment-native split-f16 (feats now dead -> aliased)
    k_pack<<<632, 256, 0, stream>>>(outx, pxh, pxl);
    k_pack<<<632, 256, 0, stream>>>(outy, pyh, pyl);
    k_final_mfma<<<NTILE * NTILE, 256, 0, stream>>>(pxh, pxl, pyh, pyl, (float*)d_out);
}

// Round 17
// 1489.688 us; speedup vs baseline: 1.1150x; 1.0763x over previous
//
#include <hip/hip_runtime.h>
#include <hip/hip_bf16.h>
#include <math.h>

#define N_NODES 10000
#define FEAT    256
#define NEDGE   320000
#define NLAYERS 5
#define NOC     128

// padded tiling for final GEMM: 79 tiles of 128 -> 10112 rows
#define NTILE   79
#define PADROWS 10112
// packed f16 fragment array (final GEMM): (10112/16) row-tiles * 4 k-steps * 64 lanes * 8
#define PACKSZ  1294336

typedef __attribute__((ext_vector_type(8))) _Float16 f16x8;
typedef __attribute__((ext_vector_type(4))) float f32x4;

// split x into f16 hi + f16 lo (x ~= hi + lo, residual ~2^-22 rel)
static __device__ inline void f16split(float x, ushort& h, ushort& l) {
    _Float16 hf = (_Float16)x;
    float hb = (float)hf;
    _Float16 lf = (_Float16)(x - hb);
    union { _Float16 f; ushort u; } ch, cl;
    ch.f = hf; cl.f = lf;
    h = ch.u; l = cl.u;
}

// ---------------- init: deg=1 (self loop), counters=0, attmax=0 ----------------
__global__ void k_init(float* deg, int* cnt, int* fill, int* attm) {
    int i = blockIdx.x * blockDim.x + threadIdx.x;
    if (i < N_NODES) { deg[i] = 1.0f; cnt[i] = 0; fill[i] = 0; }
    if (i < NLAYERS) attm[i] = 0;
}

// ---------------- degree + per-dst edge count ----------------
__global__ void k_count(const int* __restrict__ edges, const float* __restrict__ ew,
                        float* deg, int* cnt) {
    int e = blockIdx.x * blockDim.x + threadIdx.x;
    if (e >= NEDGE) return;
    int d = edges[NEDGE + e];
    atomicAdd(&deg[d], ew[e]);
    atomicAdd(&cnt[d], 1);
}

// ---------------- dinv = rsqrt(deg) in place ----------------
__global__ void k_dinv(float* deg) {
    int i = blockIdx.x * blockDim.x + threadIdx.x;
    if (i < N_NODES) {
        float dg = deg[i];
        deg[i] = (dg > 0.f) ? 1.0f / sqrtf(dg) : 0.f;
    }
}

// ---------------- single-block exclusive scan (10000 entries) ----------------
__global__ void k_scan(const int* __restrict__ cnt, int* __restrict__ ptr) {
    __shared__ int sm[1024];
    __shared__ int carry;
    int t = threadIdx.x;
    if (t == 0) carry = 0;
    __syncthreads();
    for (int base = 0; base < N_NODES; base += 1024) {
        int i = base + t;
        int v = (i < N_NODES) ? cnt[i] : 0;
        sm[t] = v;
        __syncthreads();
        for (int off = 1; off < 1024; off <<= 1) {
            int add = (t >= off) ? sm[t - off] : 0;
            __syncthreads();
            sm[t] += add;
            __syncthreads();
        }
        if (i < N_NODES) ptr[i] = carry + sm[t] - v;   // exclusive
        __syncthreads();
        if (t == 1023) carry += sm[1023];
        __syncthreads();
    }
    if (t == 0) ptr[N_NODES] = carry;
}

// ---------------- CSR fill: col + normalized coefficient ----------------
__global__ void k_fill(const int* __restrict__ edges, const float* __restrict__ ew,
                       const float* __restrict__ dinv, const int* __restrict__ ptr,
                       int* fill, int* __restrict__ col, float* __restrict__ val) {
    int e = blockIdx.x * blockDim.x + threadIdx.x;
    if (e >= NEDGE) return;
    int s = edges[e], d = edges[NEDGE + e];
    int pos = ptr[d] + atomicAdd(&fill[d], 1);
    col[pos] = s;
    val[pos] = dinv[s] * ew[e] * dinv[d];
}

// ---------------- SpMM gather: t[row] = dinv[row]^2*x[row] + sum c_e * x[col_e]
// one wave per row; 4-wide unrolled edge loop with 4 independent accumulators
// (4 outstanding 1KB row-loads per wave -> 4x memory-level parallelism).
// OUTPUT written as packed f16 hi/lo MFMA A-fragments:
//   lane l holds k = 4l..4l+3; slot = ((mt*8+ks)*64 + kg*16 + rr)*8 + e0
//   (mt=row>>4, rr=row&15, ks=l>>3, kg=(l>>1)&3, e0=(l&1)*4). 10000 = 625*16.
__global__ __launch_bounds__(256) void k_spmm(const float* __restrict__ x,
        const int* __restrict__ ptr, const int* __restrict__ col,
        const float* __restrict__ val, const float* __restrict__ dinv,
        ushort* __restrict__ th, ushort* __restrict__ tl) {
    int wave = threadIdx.x >> 6;
    int lane = threadIdx.x & 63;
    int row = blockIdx.x * 4 + wave;
    if (row >= N_NODES) return;
    float di = dinv[row];
    float selfc = di * di;
    float4 xv = ((const float4*)(x + (size_t)row * FEAT))[lane];
    float4 a0, a1, a2, a3;
    a0.x = selfc * xv.x; a0.y = selfc * xv.y; a0.z = selfc * xv.z; a0.w = selfc * xv.w;
    a1 = make_float4(0.f, 0.f, 0.f, 0.f);
    a2 = make_float4(0.f, 0.f, 0.f, 0.f);
    a3 = make_float4(0.f, 0.f, 0.f, 0.f);
    int e0 = ptr[row], e1 = ptr[row + 1];
    int e = e0;
    for (; e + 4 <= e1; e += 4) {
        int c0 = col[e], c1 = col[e + 1], c2 = col[e + 2], c3 = col[e + 3];
        float v0 = val[e], v1 = val[e + 1], v2 = val[e + 2], v3 = val[e + 3];
        float4 x0 = ((const float4*)(x + (size_t)c0 * FEAT))[lane];
        float4 x1 = ((const float4*)(x + (size_t)c1 * FEAT))[lane];
        float4 x2 = ((const float4*)(x + (size_t)c2 * FEAT))[lane];
        float4 x3 = ((const float4*)(x + (size_t)c3 * FEAT))[lane];
        a0.x += v0 * x0.x; a0.y += v0 * x0.y; a0.z += v0 * x0.z; a0.w += v0 * x0.w;
        a1.x += v1 * x1.x; a1.y += v1 * x1.y; a1.z += v1 * x1.z; a1.w += v1 * x1.w;
        a2.x += v2 * x2.x; a2.y += v2 * x2.y; a2.z += v2 * x2.z; a2.w += v2 * x2.w;
        a3.x += v3 * x3.x; a3.y += v3 * x3.y; a3.z += v3 * x3.z; a3.w += v3 * x3.w;
    }
    for (; e < e1; ++e) {
        int c = col[e];
        float cv = val[e];
        float4 v = ((const float4*)(x + (size_t)c * FEAT))[lane];
        a0.x += cv * v.x; a0.y += cv * v.y; a0.z += cv * v.z; a0.w += cv * v.w;
    }
    float4 acc;
    acc.x = (a0.x + a1.x) + (a2.x + a3.x);
    acc.y = (a0.y + a1.y) + (a2.y + a3.y);
    acc.z = (a0.z + a1.z) + (a2.z + a3.z);
    acc.w = (a0.w + a1.w) + (a2.w + a3.w);
    int mt = row >> 4, rr = row & 15;
    int ks = lane >> 3, kg = (lane >> 1) & 3, ee = (lane & 1) * 4;
    size_t pb = ((size_t)(mt * 8 + ks) * 64 + kg * 16 + rr) * 8 + ee;
    ushort h[4], l[4];
    f16split(acc.x, h[0], l[0]); f16split(acc.y, h[1], l[1]);
    f16split(acc.z, h[2], l[2]); f16split(acc.w, h[3], l[3]);
    *(uint2*)(th + pb) = make_uint2((uint)h[0] | ((uint)h[1] << 16),
                                    (uint)h[2] | ((uint)h[3] << 16));
    *(uint2*)(tl + pb) = make_uint2((uint)l[0] | ((uint)l[1] << 16),
                                    (uint)l[2] | ((uint)l[3] << 16));
}

// ---------------- pack W [5][256][256] (W[l][k][n]) -> f16 hi/lo B-fragments ---
// B-frag slot (per layer): ((nt*8+ks)*64 + kg*16 + rc)*8 + e ; n=nt*16+rc, k=ks*32+kg*8+e
__global__ void k_packW(const float* __restrict__ W, ushort* __restrict__ wh,
                        ushort* __restrict__ wl) {
    int g = blockIdx.x * blockDim.x + threadIdx.x;
    if (g >= NLAYERS * 8192) return;
    int l = g >> 13, gl = g & 8191;
    int rc = gl & 15, kg = (gl >> 4) & 3, ks = (gl >> 6) & 7, nt = gl >> 9;
    int n = nt * 16 + rc, k0 = ks * 32 + kg * 8;
    const float* src = W + (size_t)l * 65536 + (size_t)k0 * 256 + n;
    uint hw[4], lw[4];
#pragma unroll
    for (int e = 0; e < 8; e += 2) {
        ushort h0, l0, h1, l1;
        f16split(src[(size_t)e * 256], h0, l0);
        f16split(src[(size_t)(e + 1) * 256], h1, l1);
        hw[e >> 1] = (uint)h0 | ((uint)h1 << 16);
        lw[e >> 1] = (uint)l0 | ((uint)l1 << 16);
    }
    size_t dst = (size_t)g * 8;
    *(uint4*)(wh + dst) = make_uint4(hw[0], hw[1], hw[2], hw[3]);
    *(uint4*)(wl + dst) = make_uint4(lw[0], lw[1], lw[2], lw[3]);
}

// ---------------- layer GEMM via f16-split MFMA --------------------------------
// out[m,n] = relu( sum_k t[m,k] W[k,n] + bias[n] ), m<10000, n<256, K=256
// C ~= ThWh + ThWl + TlWh (lo*lo dropped, ~2^-22 rel: fp32-level).
// 128x128 block tile, 4 waves of 64x64, fused bias+relu+feats-store+max->attm.
__global__ __launch_bounds__(256) void k_gemm_l(
        const ushort* __restrict__ th, const ushort* __restrict__ tl,
        const ushort* __restrict__ wh, const ushort* __restrict__ wl,
        const float* __restrict__ bias, float* __restrict__ out, int* attm) {
    __shared__ float red[256];
    int tid = threadIdx.x;
    int wave = tid >> 6, lane = tid & 63;
    int m0 = blockIdx.x * 128 + (wave >> 1) * 64;
    int n0 = blockIdx.y * 128 + (wave & 1) * 64;
    int mtb = m0 >> 4, ntb = n0 >> 4;

    f32x4 acc[4][4];
#pragma unroll
    for (int i = 0; i < 4; ++i)
#pragma unroll
        for (int j = 0; j < 4; ++j) acc[i][j] = (f32x4){0.f, 0.f, 0.f, 0.f};

#pragma unroll
    for (int ks = 0; ks < 8; ++ks) {
        f16x8 ah[4], al[4], bh[4], bl[4];
#pragma unroll
        for (int i = 0; i < 4; ++i) {
            int mt = mtb + i; if (mt > 624) mt = 624;   // rows>=10000 discarded below
            size_t ao = ((size_t)(mt * 8 + ks) * 64 + lane) * 8;
            size_t bo = ((size_t)((ntb + i) * 8 + ks) * 64 + lane) * 8;
            ah[i] = *(const f16x8*)(th + ao);
            al[i] = *(const f16x8*)(tl + ao);
            bh[i] = *(const f16x8*)(wh + bo);
            bl[i] = *(const f16x8*)(wl + bo);
        }
#pragma unroll
        for (int i = 0; i < 4; ++i)
#pragma unroll
            for (int j = 0; j < 4; ++j) {
                acc[i][j] = __builtin_amdgcn_mfma_f32_16x16x32_f16(ah[i], bh[j], acc[i][j], 0, 0, 0);
                acc[i][j] = __builtin_amdgcn_mfma_f32_16x16x32_f16(ah[i], bl[j], acc[i][j], 0, 0, 0);
                acc[i][j] = __builtin_amdgcn_mfma_f32_16x16x32_f16(al[i], bh[j], acc[i][j], 0, 0, 0);
            }
    }

    // D layout: row=(lane>>4)*4+reg, col=lane&15
    int rbase = (lane >> 4) * 4, cn = lane & 15;
    float lmax = 0.f;
#pragma unroll
    for (int i = 0; i < 4; ++i)
#pragma unroll
        for (int j = 0; j < 4; ++j) {
            int n = n0 + j * 16 + cn;
            float bv = bias[n];
#pragma unroll
            for (int rr = 0; rr < 4; ++rr) {
                int m = m0 + i * 16 + rbase + rr;
                if (m < N_NODES) {
                    float v = fmaxf(acc[i][j][rr] + bv, 0.f);
                    lmax = fmaxf(lmax, v);
                    out[(size_t)m * FEAT + n] = v;
                }
            }
        }
    red[tid] = lmax;
    __syncthreads();
    for (int s = 128; s > 0; s >>= 1) {
        if (tid < s) red[tid] = fmaxf(red[tid], red[tid + s]);
        __syncthreads();
    }
    if (tid == 0) atomicMax(attm, __float_as_int(red[0]));   // all values >= 0
}

// ---------------- tiled fp32 GEMM (branch-out only): C = A@B + bias ------------
// 64x64 tile, 256 threads, 4x4/thread. chunked: A[n,k] = feats[(k>>8)*10000+n][k&255]
__global__ __launch_bounds__(256) void k_gemm(const float* __restrict__ A,
        const float* __restrict__ B, const float* __restrict__ bias,
        float* __restrict__ C, int M, int N, int K, int chunked,
        int* attm, int do_relu) {
    __shared__ float As[16][68];
    __shared__ float Bs[16][68];
    int tid = threadIdx.x;
    int tx = tid & 15, ty = tid >> 4;
    int m0 = blockIdx.x * 64, n0 = blockIdx.y * 64;
    float acc[4][4];
#pragma unroll
    for (int i = 0; i < 4; ++i)
#pragma unroll
        for (int j = 0; j < 4; ++j) acc[i][j] = 0.f;

    int arow = m0 + (tid >> 2); if (arow >= M) arow = M - 1;
    int am = tid >> 2;
    int akk = (tid & 3) * 4;
    int bk = tid >> 4;
    int bn = (tid & 15) * 4;

    for (int k0 = 0; k0 < K; k0 += 16) {
        int ka = k0 + akk;
        float4 av;
        if (chunked)
            av = *(const float4*)(A + ((size_t)(ka >> 8) * N_NODES + arow) * FEAT + (ka & 255));
        else
            av = *(const float4*)(A + (size_t)arow * K + ka);
        float4 bv = *(const float4*)(B + (size_t)(k0 + bk) * N + (n0 + bn));
        __syncthreads();
        As[akk + 0][am] = av.x;
        As[akk + 1][am] = av.y;
        As[akk + 2][am] = av.z;
        As[akk + 3][am] = av.w;
        *(float4*)&Bs[bk][bn] = bv;
        __syncthreads();
#pragma unroll
        for (int kk = 0; kk < 16; ++kk) {
            float4 a4 = *(const float4*)&As[kk][ty * 4];
            float4 b4 = *(const float4*)&Bs[kk][tx * 4];
            float a[4] = {a4.x, a4.y, a4.z, a4.w};
            float b[4] = {b4.x, b4.y, b4.z, b4.w};
#pragma unroll
            for (int i = 0; i < 4; ++i)
#pragma unroll
                for (int j = 0; j < 4; ++j) acc[i][j] += a[i] * b[j];
        }
    }

    float lmax = 0.f;
#pragma unroll
    for (int i = 0; i < 4; ++i) {
        int m = m0 + ty * 4 + i;
        if (m < M) {
            float vals[4];
#pragma unroll
            for (int j = 0; j < 4; ++j) {
                float v = acc[i][j] + bias[n0 + tx * 4 + j];
                if (do_relu) { v = fmaxf(v, 0.f); lmax = fmaxf(lmax, v); }
                vals[j] = v;
            }
            *(float4*)(C + (size_t)m * N + n0 + tx * 4) =
                make_float4(vals[0], vals[1], vals[2], vals[3]);
        }
    }
    if (do_relu) {
        __syncthreads();
        float* red = (float*)As;
        red[tid] = lmax;
        __syncthreads();
        for (int s = 128; s > 0; s >>= 1) {
            if (tid < s) red[tid] = fmaxf(red[tid], red[tid + s]);
            __syncthreads();
        }
        if (tid == 0) atomicMax(attm, __float_as_int(red[0]));
    }
}

// ---------------- attention MLP (5 -> 25 relu -> 5 sigmoid), one tiny block ----
__global__ void k_att(const int* __restrict__ attm, const float* __restrict__ fc1w,
                      const float* __restrict__ fc1b, const float* __restrict__ fc2w,
                      const float* __restrict__ fc2b, float* __restrict__ att) {
    __shared__ float a0[NLAYERS], a1[5 * NLAYERS];
    int t = threadIdx.x;
    if (t < NLAYERS) a0[t] = __int_as_float(attm[t]);
    __syncthreads();
    if (t < 5 * NLAYERS) {
        float s = fc1b[t];
        for (int c = 0; c < NLAYERS; ++c) s += fc1w[t * NLAYERS + c] * a0[c];
        a1[t] = fmaxf(s, 0.f);
    }
    __syncthreads();
    if (t < NLAYERS) {
        float s = fc2b[t];
        for (int c = 0; c < 5 * NLAYERS; ++c) s += fc2w[t * 5 * NLAYERS + c] * a1[c];
        att[t] = 1.f / (1.f + expf(-s));
    }
}

// ---------------- B'[k*128+o] = cw[o*1280+k] * att[k>>8] ----------------
__global__ void k_bprime(const float* __restrict__ cw, const float* __restrict__ att,
                         float* __restrict__ bp) {
    int idx = blockIdx.x * blockDim.x + threadIdx.x;
    if (idx >= NLAYERS * FEAT * NOC) return;
    int k = idx >> 7;                       // 0..1279
    int o = idx & (NOC - 1);
    bp[idx] = cw[(size_t)o * (NLAYERS * FEAT) + k] * att[k >> 8];
}

// ---------------- split-f16 pack for the final MFMA GEMM ----------------------
// src[row][k] fp32 (10000x128) -> hi/lo f16 fragment-native; rows>=10000 zeroed.
__global__ __launch_bounds__(256) void k_pack(const float* __restrict__ src,
        ushort* __restrict__ hi, ushort* __restrict__ lo) {
    int t = blockIdx.x * blockDim.x + threadIdx.x;     // 10112*16 = 161792 threads
    int row = t >> 4;
    int g = t & 15;                                    // which group of 8 k's
    int mt = row >> 4, rr = row & 15;
    int ks = g >> 2, kg = g & 3;
    size_t dst = ((size_t)(mt * 4 + ks) * 64 + kg * 16 + rr) * 8;
    uint h[4] = {0, 0, 0, 0}, l[4] = {0, 0, 0, 0};
    if (row < N_NODES) {
        const float* p = src + (size_t)row * NOC + g * 8;
#pragma unroll
        for (int e = 0; e < 8; ++e) {
            ushort hu, lu;
            f16split(p[e], hu, lu);
            h[e >> 1] |= (uint)hu << ((e & 1) * 16);
            l[e >> 1] |= (uint)lu << ((e & 1) * 16);
        }
    }
    *(uint4*)(hi + dst) = make_uint4(h[0], h[1], h[2], h[3]);
    *(uint4*)(lo + dst) = make_uint4(l[0], l[1], l[2], l[3]);
}

// ---------------- final C[10000,10000] = X @ Y^T via split-f16 MFMA -----------
__global__ __launch_bounds__(256) void k_final_mfma(
        const ushort* __restrict__ xh, const ushort* __restrict__ xl,
        const ushort* __restrict__ yh, const ushort* __restrict__ yl,
        float* __restrict__ C) {
    // bijective XCD swizzle (nwg = 6241 = 8*780 + 1)
    int bid = blockIdx.x;
    const int nwg = NTILE * NTILE;
    const int q = nwg >> 3, r = nwg & 7;
    int xcd = bid & 7, loc = bid >> 3;
    int wg = (xcd < r ? xcd * (q + 1) : r * (q + 1) + (xcd - r) * q) + loc;
    int tm = wg / NTILE, tn = wg % NTILE;

    int tid = threadIdx.x;
    int wave = tid >> 6, lane = tid & 63;
    int m0 = tm * 128 + (wave >> 1) * 64;
    int n0 = tn * 128 + (wave & 1) * 64;
    int mtb = m0 >> 4, ntb = n0 >> 4;

    f32x4 acc[4][4];
#pragma unroll
    for (int i = 0; i < 4; ++i)
#pragma unroll
        for (int j = 0; j < 4; ++j) acc[i][j] = (f32x4){0.f, 0.f, 0.f, 0.f};

#pragma unroll
    for (int ks = 0; ks < 4; ++ks) {
        f16x8 ah[4], al[4], bh[4], bl[4];
#pragma unroll
        for (int i = 0; i < 4; ++i) {
            size_t ao = ((size_t)((mtb + i) * 4 + ks) * 64 + lane) * 8;
            size_t bo = ((size_t)((ntb + i) * 4 + ks) * 64 + lane) * 8;
            ah[i] = *(const f16x8*)(xh + ao);
            al[i] = *(const f16x8*)(xl + ao);
            bh[i] = *(const f16x8*)(yh + bo);
            bl[i] = *(const f16x8*)(yl + bo);
        }
#pragma unroll
        for (int i = 0; i < 4; ++i)
#pragma unroll
            for (int j = 0; j < 4; ++j) {
                acc[i][j] = __builtin_amdgcn_mfma_f32_16x16x32_f16(ah[i], bh[j], acc[i][j], 0, 0, 0);
                acc[i][j] = __builtin_amdgcn_mfma_f32_16x16x32_f16(ah[i], bl[j], acc[i][j], 0, 0, 0);
                acc[i][j] = __builtin_amdgcn_mfma_f32_16x16x32_f16(al[i], bh[j], acc[i][j], 0, 0, 0);
            }
    }

    // D frag layout: row = (lane>>4)*4 + reg, col = lane&15
    int rbase = (lane >> 4) * 4, cn = lane & 15;
    bool full = (m0 + 63 < N_NODES) && (n0 + 63 < N_NODES);
    if (full) {
#pragma unroll
        for (int i = 0; i < 4; ++i)
#pragma unroll
            for (int j = 0; j < 4; ++j) {
                size_t base = (size_t)(m0 + i * 16 + rbase) * N_NODES + (n0 + j * 16 + cn);
#pragma unroll
                for (int rr = 0; rr < 4; ++rr)
                    C[base + (size_t)rr * N_NODES] = acc[i][j][rr];
            }
    } else {
        for (int i = 0; i < 4; ++i)
            for (int j = 0; j < 4; ++j) {
                int ccol = n0 + j * 16 + cn;
                if (ccol >= N_NODES) continue;
                for (int rr = 0; rr < 4; ++rr) {
                    int mr = m0 + i * 16 + rbase + rr;
                    if (mr < N_NODES)
                        C[(size_t)mr * N_NODES + ccol] = acc[i][j][rr];
                }
            }
    }
}

extern "C" void kernel_launch(void* const* d_in, const int* in_sizes, int n_in,
                              void* d_out, int out_size, void* d_ws, size_t ws_size,
                              hipStream_t stream) {
    (void)in_sizes; (void)n_in; (void)out_size; (void)ws_size;

    // ---- workspace carve-up (identical footprint to verified round-9 layout) ----
    float* ws     = (float*)d_ws;
    float* feats  = ws;                          // 5*10000*256 = 12,800,000
    float* tbuf   = feats + 12800000;            // 2,560,000 (holds th/tl packed)
    float* outx   = tbuf + 2560000;              // 1,280,000
    float* outy   = outx + 1280000;              // 1,280,000
    float* dinv   = outy + 1280000;              // 10,016
    float* val    = dinv + 10016;                // 320,000
    float* bprime = val + 320000;                // 163,840
    float* attF   = bprime + 163840;             // 16
    int*   ptr    = (int*)(attF + 16);           // 10,016
    int*   cnt    = ptr + 10016;                 // 10,016
    int*   fill   = cnt + 10016;                 // 10,016
    int*   col    = fill + 10016;                // 320,000
    int*   attm   = col + 320000;                // 16

    // packed f16 t (A-side, per layer): exactly fills tbuf (2*2.56M ushorts)
    ushort* th = (ushort*)tbuf;
    ushort* tl = th + 2560000;
    // packed f16 W (B-side, 5 layers): aliases outy (outy written only at branch-1
    // end, after the last layer GEMM of branch 1 -> no overlap in lifetime)
    ushort* Wh = (ushort*)outy;
    ushort* Wl = Wh + NLAYERS * 65536;           // 2*327,680 ushorts = 327,680 floats

    // final-GEMM packed operands alias feats (dead after branch-out GEMMs)
    ushort* pxh = (ushort*)feats;
    ushort* pxl = pxh + PACKSZ;
    ushort* pyh = pxl + PACKSZ;
    ushort* pyl = pyh + PACKSZ;

    for (int b = 0; b < 2; ++b) {
        const float* x0   = (const float*)d_in[b == 0 ? 0 : 1];
        const float* ew   = (const float*)d_in[b == 0 ? 2 : 3];
        const float* W    = (const float*)d_in[b == 0 ? 4 : 6];
        const float* bias = (const float*)d_in[b == 0 ? 5 : 7];
        const float* fc1w = (const float*)d_in[b == 0 ? 8 : 12];
        const float* fc1b = (const float*)d_in[b == 0 ? 9 : 13];
        const float* fc2w = (const float*)d_in[b == 0 ? 10 : 14];
        const float* fc2b = (const float*)d_in[b == 0 ? 11 : 15];
        const float* cw   = (const float*)d_in[b == 0 ? 16 : 18];
        const float* cb   = (const float*)d_in[b == 0 ? 17 : 19];
        const int* edges  = (const int*)d_in[b == 0 ? 20 : 21];
        float* outb = (b == 0) ? outx : outy;

        k_init<<<40, 256, 0, stream>>>(dinv, cnt, fill, attm);
        k_count<<<1250, 256, 0, stream>>>(edges, ew, dinv, cnt);
        k_dinv<<<40, 256, 0, stream>>>(dinv);
        k_scan<<<1, 1024, 0, stream>>>(cnt, ptr);
        k_fill<<<1250, 256, 0, stream>>>(edges, ew, dinv, ptr, fill, col, val);
        k_packW<<<160, 256, 0, stream>>>(W, Wh, Wl);

        for (int l = 0; l < NLAYERS; ++l) {
            const float* prev = (l == 0) ? x0 : (feats + (size_t)(l - 1) * N_NODES * FEAT);
            k_spmm<<<2500, 256, 0, stream>>>(prev, ptr, col, val, dinv, th, tl);
            k_gemm_l<<<dim3(79, 2), 256, 0, stream>>>(
                th, tl, Wh + (size_t)l * 65536, Wl + (size_t)l * 65536,
                bias + (size_t)l * FEAT,
                feats + (size_t)l * N_NODES * FEAT, attm + l);
        }

        k_att<<<1, 64, 0, stream>>>(attm, fc1w, fc1b, fc2w, fc2b, attF);
        k_bprime<<<640, 256, 0, stream>>>(cw, attF, bprime);
        k_gemm<<<dim3(157, 2), 256, 0, stream>>>(
            feats, bprime, cb, outb, N_NODES, NOC, NLAYERS * FEAT, 1, nullptr, 0);
    }

    // pack outx/outy into fragment-native split-f16 (feats now dead -> aliased)
    k_pack<<<632, 256, 0, stream>>>(outx, pxh, pxl);
    k_pack<<<632, 256, 0, stream>>>(outy, pyh, pyl);
    k_final_mfma<<<NTILE * NTILE, 256, 0, stream>>>(pxh, pxl, pyh, pyl, (float*)d_out);
}

// Round 18
// 1412.726 us; speedup vs baseline: 1.1757x; 1.0545x over previous
//
#include <hip/hip_runtime.h>
#include <hip/hip_bf16.h>
#include <math.h>

#define N_NODES 10000
#define FEAT    256
#define NEDGE   320000
#define NLAYERS 5
#define NOC     128

// padded tiling for final GEMM: 79 tiles of 128 -> 10112 rows
#define NTILE   79
#define PADROWS 10112
// packed f16 fragment array (final GEMM): (10112/16) row-tiles * 4 k-steps * 64 lanes * 8
#define PACKSZ  1294336

typedef __attribute__((ext_vector_type(8))) _Float16 f16x8;
typedef __attribute__((ext_vector_type(4))) float f32x4;

// split x into f16 hi + f16 lo (x ~= hi + lo, residual ~2^-22 rel)
static __device__ inline void f16split(float x, ushort& h, ushort& l) {
    _Float16 hf = (_Float16)x;
    float hb = (float)hf;
    _Float16 lf = (_Float16)(x - hb);
    union { _Float16 f; ushort u; } ch, cl;
    ch.f = hf; cl.f = lf;
    h = ch.u; l = cl.u;
}

// ---------------- init: deg=1 (self loop), counters=0, attmax=0 ----------------
__global__ void k_init(float* deg, int* cnt, int* fill, int* attm) {
    int i = blockIdx.x * blockDim.x + threadIdx.x;
    if (i < N_NODES) { deg[i] = 1.0f; cnt[i] = 0; fill[i] = 0; }
    if (i < NLAYERS) attm[i] = 0;
}

// ---------------- degree + per-dst edge count ----------------
__global__ void k_count(const int* __restrict__ edges, const float* __restrict__ ew,
                        float* deg, int* cnt) {
    int e = blockIdx.x * blockDim.x + threadIdx.x;
    if (e >= NEDGE) return;
    int d = edges[NEDGE + e];
    atomicAdd(&deg[d], ew[e]);
    atomicAdd(&cnt[d], 1);
}

// ---------------- dinv = rsqrt(deg) in place ----------------
__global__ void k_dinv(float* deg) {
    int i = blockIdx.x * blockDim.x + threadIdx.x;
    if (i < N_NODES) {
        float dg = deg[i];
        deg[i] = (dg > 0.f) ? 1.0f / sqrtf(dg) : 0.f;
    }
}

// ---------------- single-block exclusive scan (10000 entries) ----------------
__global__ void k_scan(const int* __restrict__ cnt, int* __restrict__ ptr) {
    __shared__ int sm[1024];
    __shared__ int carry;
    int t = threadIdx.x;
    if (t == 0) carry = 0;
    __syncthreads();
    for (int base = 0; base < N_NODES; base += 1024) {
        int i = base + t;
        int v = (i < N_NODES) ? cnt[i] : 0;
        sm[t] = v;
        __syncthreads();
        for (int off = 1; off < 1024; off <<= 1) {
            int add = (t >= off) ? sm[t - off] : 0;
            __syncthreads();
            sm[t] += add;
            __syncthreads();
        }
        if (i < N_NODES) ptr[i] = carry + sm[t] - v;   // exclusive
        __syncthreads();
        if (t == 1023) carry += sm[1023];
        __syncthreads();
    }
    if (t == 0) ptr[N_NODES] = carry;
}

// ---------------- CSR fill: col + normalized coefficient ----------------
__global__ void k_fill(const int* __restrict__ edges, const float* __restrict__ ew,
                       const float* __restrict__ dinv, const int* __restrict__ ptr,
                       int* fill, int* __restrict__ col, float* __restrict__ val) {
    int e = blockIdx.x * blockDim.x + threadIdx.x;
    if (e >= NEDGE) return;
    int s = edges[e], d = edges[NEDGE + e];
    int pos = ptr[d] + atomicAdd(&fill[d], 1);
    col[pos] = s;
    val[pos] = dinv[s] * ew[e] * dinv[d];
}

// ---------------- SpMM gather: t[row] = dinv[row]^2*x[row] + sum c_e * x[col_e]
// one wave per row; 4-wide unrolled edge loop with 4 independent accumulators
// (4 outstanding 1KB row-loads per wave -> 4x memory-level parallelism).
// OUTPUT written as packed f16 hi/lo MFMA A-fragments:
//   lane l holds k = 4l..4l+3; slot = ((mt*8+ks)*64 + kg*16 + rr)*8 + e0
//   (mt=row>>4, rr=row&15, ks=l>>3, kg=(l>>1)&3, e0=(l&1)*4). 10000 = 625*16.
__global__ __launch_bounds__(256) void k_spmm(const float* __restrict__ x,
        const int* __restrict__ ptr, const int* __restrict__ col,
        const float* __restrict__ val, const float* __restrict__ dinv,
        ushort* __restrict__ th, ushort* __restrict__ tl) {
    int wave = threadIdx.x >> 6;
    int lane = threadIdx.x & 63;
    int row = blockIdx.x * 4 + wave;
    if (row >= N_NODES) return;
    float di = dinv[row];
    float selfc = di * di;
    float4 xv = ((const float4*)(x + (size_t)row * FEAT))[lane];
    float4 a0, a1, a2, a3;
    a0.x = selfc * xv.x; a0.y = selfc * xv.y; a0.z = selfc * xv.z; a0.w = selfc * xv.w;
    a1 = make_float4(0.f, 0.f, 0.f, 0.f);
    a2 = make_float4(0.f, 0.f, 0.f, 0.f);
    a3 = make_float4(0.f, 0.f, 0.f, 0.f);
    int e0 = ptr[row], e1 = ptr[row + 1];
    int e = e0;
    for (; e + 4 <= e1; e += 4) {
        int c0 = col[e], c1 = col[e + 1], c2 = col[e + 2], c3 = col[e + 3];
        float v0 = val[e], v1 = val[e + 1], v2 = val[e + 2], v3 = val[e + 3];
        float4 x0 = ((const float4*)(x + (size_t)c0 * FEAT))[lane];
        float4 x1 = ((const float4*)(x + (size_t)c1 * FEAT))[lane];
        float4 x2 = ((const float4*)(x + (size_t)c2 * FEAT))[lane];
        float4 x3 = ((const float4*)(x + (size_t)c3 * FEAT))[lane];
        a0.x += v0 * x0.x; a0.y += v0 * x0.y; a0.z += v0 * x0.z; a0.w += v0 * x0.w;
        a1.x += v1 * x1.x; a1.y += v1 * x1.y; a1.z += v1 * x1.z; a1.w += v1 * x1.w;
        a2.x += v2 * x2.x; a2.y += v2 * x2.y; a2.z += v2 * x2.z; a2.w += v2 * x2.w;
        a3.x += v3 * x3.x; a3.y += v3 * x3.y; a3.z += v3 * x3.z; a3.w += v3 * x3.w;
    }
    for (; e < e1; ++e) {
        int c = col[e];
        float cv = val[e];
        float4 v = ((const float4*)(x + (size_t)c * FEAT))[lane];
        a0.x += cv * v.x; a0.y += cv * v.y; a0.z += cv * v.z; a0.w += cv * v.w;
    }
    float4 acc;
    acc.x = (a0.x + a1.x) + (a2.x + a3.x);
    acc.y = (a0.y + a1.y) + (a2.y + a3.y);
    acc.z = (a0.z + a1.z) + (a2.z + a3.z);
    acc.w = (a0.w + a1.w) + (a2.w + a3.w);
    int mt = row >> 4, rr = row & 15;
    int ks = lane >> 3, kg = (lane >> 1) & 3, ee = (lane & 1) * 4;
    size_t pb = ((size_t)(mt * 8 + ks) * 64 + kg * 16 + rr) * 8 + ee;
    ushort h[4], l[4];
    f16split(acc.x, h[0], l[0]); f16split(acc.y, h[1], l[1]);
    f16split(acc.z, h[2], l[2]); f16split(acc.w, h[3], l[3]);
    *(uint2*)(th + pb) = make_uint2((uint)h[0] | ((uint)h[1] << 16),
                                    (uint)h[2] | ((uint)h[3] << 16));
    *(uint2*)(tl + pb) = make_uint2((uint)l[0] | ((uint)l[1] << 16),
                                    (uint)l[2] | ((uint)l[3] << 16));
}

// ---------------- pack W [5][256][256] (W[l][k][n]) -> f16 hi/lo B-fragments ---
// B-frag slot (per layer): ((nt*8+ks)*64 + kg*16 + rc)*8 + e ; n=nt*16+rc, k=ks*32+kg*8+e
__global__ void k_packW(const float* __restrict__ W, ushort* __restrict__ wh,
                        ushort* __restrict__ wl) {
    int g = blockIdx.x * blockDim.x + threadIdx.x;
    if (g >= NLAYERS * 8192) return;
    int l = g >> 13, gl = g & 8191;
    int rc = gl & 15, kg = (gl >> 4) & 3, ks = (gl >> 6) & 7, nt = gl >> 9;
    int n = nt * 16 + rc, k0 = ks * 32 + kg * 8;
    const float* src = W + (size_t)l * 65536 + (size_t)k0 * 256 + n;
    uint hw[4], lw[4];
#pragma unroll
    for (int e = 0; e < 8; e += 2) {
        ushort h0, l0, h1, l1;
        f16split(src[(size_t)e * 256], h0, l0);
        f16split(src[(size_t)(e + 1) * 256], h1, l1);
        hw[e >> 1] = (uint)h0 | ((uint)h1 << 16);
        lw[e >> 1] = (uint)l0 | ((uint)l1 << 16);
    }
    size_t dst = (size_t)g * 8;
    *(uint4*)(wh + dst) = make_uint4(hw[0], hw[1], hw[2], hw[3]);
    *(uint4*)(wl + dst) = make_uint4(lw[0], lw[1], lw[2], lw[3]);
}

// ---------------- layer GEMM via f16-split MFMA --------------------------------
// out[m,n] = relu( sum_k t[m,k] W[k,n] + bias[n] ), m<10000, n<256, K=256
// C ~= ThWh + ThWl + TlWh (lo*lo dropped, ~2^-22 rel: fp32-level).
// 128x128 block tile, 4 waves of 64x64, fused bias+relu+feats-store+max->attm.
__global__ __launch_bounds__(256) void k_gemm_l(
        const ushort* __restrict__ th, const ushort* __restrict__ tl,
        const ushort* __restrict__ wh, const ushort* __restrict__ wl,
        const float* __restrict__ bias, float* __restrict__ out, int* attm) {
    __shared__ float red[256];
    int tid = threadIdx.x;
    int wave = tid >> 6, lane = tid & 63;
    int m0 = blockIdx.x * 128 + (wave >> 1) * 64;
    int n0 = blockIdx.y * 128 + (wave & 1) * 64;
    int mtb = m0 >> 4, ntb = n0 >> 4;

    f32x4 acc[4][4];
#pragma unroll
    for (int i = 0; i < 4; ++i)
#pragma unroll
        for (int j = 0; j < 4; ++j) acc[i][j] = (f32x4){0.f, 0.f, 0.f, 0.f};

#pragma unroll
    for (int ks = 0; ks < 8; ++ks) {
        f16x8 ah[4], al[4], bh[4], bl[4];
#pragma unroll
        for (int i = 0; i < 4; ++i) {
            int mt = mtb + i; if (mt > 624) mt = 624;   // rows>=10000 discarded below
            size_t ao = ((size_t)(mt * 8 + ks) * 64 + lane) * 8;
            size_t bo = ((size_t)((ntb + i) * 8 + ks) * 64 + lane) * 8;
            ah[i] = *(const f16x8*)(th + ao);
            al[i] = *(const f16x8*)(tl + ao);
            bh[i] = *(const f16x8*)(wh + bo);
            bl[i] = *(const f16x8*)(wl + bo);
        }
#pragma unroll
        for (int i = 0; i < 4; ++i)
#pragma unroll
            for (int j = 0; j < 4; ++j) {
                acc[i][j] = __builtin_amdgcn_mfma_f32_16x16x32_f16(ah[i], bh[j], acc[i][j], 0, 0, 0);
                acc[i][j] = __builtin_amdgcn_mfma_f32_16x16x32_f16(ah[i], bl[j], acc[i][j], 0, 0, 0);
                acc[i][j] = __builtin_amdgcn_mfma_f32_16x16x32_f16(al[i], bh[j], acc[i][j], 0, 0, 0);
            }
    }

    // D layout: row=(lane>>4)*4+reg, col=lane&15
    int rbase = (lane >> 4) * 4, cn = lane & 15;
    float lmax = 0.f;
#pragma unroll
    for (int i = 0; i < 4; ++i)
#pragma unroll
        for (int j = 0; j < 4; ++j) {
            int n = n0 + j * 16 + cn;
            float bv = bias[n];
#pragma unroll
            for (int rr = 0; rr < 4; ++rr) {
                int m = m0 + i * 16 + rbase + rr;
                if (m < N_NODES) {
                    float v = fmaxf(acc[i][j][rr] + bv, 0.f);
                    lmax = fmaxf(lmax, v);
                    out[(size_t)m * FEAT + n] = v;
                }
            }
        }
    red[tid] = lmax;
    __syncthreads();
    for (int s = 128; s > 0; s >>= 1) {
        if (tid < s) red[tid] = fmaxf(red[tid], red[tid + s]);
        __syncthreads();
    }
    if (tid == 0) atomicMax(attm, __float_as_int(red[0]));   // all values >= 0
}

// ---------------- branch-out GEMM via f16-split MFMA ---------------------------
// out[m,o] = sum_k A[m,k]*B'[k,o] + cb[o]; m<10000, o<128, K=1280.
// A[m,k] = feats[k>>8][m][k&255] fp32, converted to f16 hi/lo in-flight
// (lanes l,l+16,l+32,l+48 share a row -> full 64B-line use). B' pre-packed frags.
// 64-row blocks (grid 157 covers 10048 rows), 4 waves of 32x64.
__global__ __launch_bounds__(256) void k_gemm_out(const float* __restrict__ A,
        const ushort* __restrict__ bph, const ushort* __restrict__ bpl,
        const float* __restrict__ cb, float* __restrict__ out) {
    int tid = threadIdx.x;
    int wave = tid >> 6, lane = tid & 63;
    int m0 = blockIdx.x * 64 + (wave >> 1) * 32;
    int n0 = (wave & 1) * 64;
    int ntb = n0 >> 4;

    f32x4 acc[2][4];
#pragma unroll
    for (int i = 0; i < 2; ++i)
#pragma unroll
        for (int j = 0; j < 4; ++j) acc[i][j] = (f32x4){0.f, 0.f, 0.f, 0.f};

    for (int ks = 0; ks < 40; ++ks) {
        int layer = ks >> 3;
        int kkb = (ks & 7) * 32 + (lane >> 4) * 8;
        f16x8 ah[2], al[2], bh[4], bl[4];
#pragma unroll
        for (int i = 0; i < 2; ++i) {
            int r = m0 + i * 16 + (lane & 15);
            if (r >= N_NODES) r = N_NODES - 1;     // stores guarded below
            const float* src = A + (size_t)layer * ((size_t)N_NODES * FEAT)
                                 + (size_t)r * FEAT + kkb;
            float4 v0 = *(const float4*)(src);
            float4 v1 = *(const float4*)(src + 4);
            float tmp[8] = {v0.x, v0.y, v0.z, v0.w, v1.x, v1.y, v1.z, v1.w};
            union { f16x8 v; ushort u[8]; } H, L;
#pragma unroll
            for (int e = 0; e < 8; ++e) f16split(tmp[e], H.u[e], L.u[e]);
            ah[i] = H.v; al[i] = L.v;
        }
#pragma unroll
        for (int j = 0; j < 4; ++j) {
            size_t bo = ((size_t)((ntb + j) * 40 + ks) * 64 + lane) * 8;
            bh[j] = *(const f16x8*)(bph + bo);
            bl[j] = *(const f16x8*)(bpl + bo);
        }
#pragma unroll
        for (int i = 0; i < 2; ++i)
#pragma unroll
            for (int j = 0; j < 4; ++j) {
                acc[i][j] = __builtin_amdgcn_mfma_f32_16x16x32_f16(ah[i], bh[j], acc[i][j], 0, 0, 0);
                acc[i][j] = __builtin_amdgcn_mfma_f32_16x16x32_f16(ah[i], bl[j], acc[i][j], 0, 0, 0);
                acc[i][j] = __builtin_amdgcn_mfma_f32_16x16x32_f16(al[i], bh[j], acc[i][j], 0, 0, 0);
            }
    }

    // D layout: row=(lane>>4)*4+reg, col=lane&15
    int rbase = (lane >> 4) * 4, cn = lane & 15;
#pragma unroll
    for (int i = 0; i < 2; ++i)
#pragma unroll
        for (int j = 0; j < 4; ++j) {
            int c = n0 + j * 16 + cn;
            float bv = cb[c];
#pragma unroll
            for (int rr = 0; rr < 4; ++rr) {
                int m = m0 + i * 16 + rbase + rr;
                if (m < N_NODES)
                    out[(size_t)m * NOC + c] = acc[i][j][rr] + bv;
            }
        }
}

// ---------------- attention MLP (5 -> 25 relu -> 5 sigmoid), one tiny block ----
__global__ void k_att(const int* __restrict__ attm, const float* __restrict__ fc1w,
                      const float* __restrict__ fc1b, const float* __restrict__ fc2w,
                      const float* __restrict__ fc2b, float* __restrict__ att) {
    __shared__ float a0[NLAYERS], a1[5 * NLAYERS];
    int t = threadIdx.x;
    if (t < NLAYERS) a0[t] = __int_as_float(attm[t]);
    __syncthreads();
    if (t < 5 * NLAYERS) {
        float s = fc1b[t];
        for (int c = 0; c < NLAYERS; ++c) s += fc1w[t * NLAYERS + c] * a0[c];
        a1[t] = fmaxf(s, 0.f);
    }
    __syncthreads();
    if (t < NLAYERS) {
        float s = fc2b[t];
        for (int c = 0; c < 5 * NLAYERS; ++c) s += fc2w[t * 5 * NLAYERS + c] * a1[c];
        att[t] = 1.f / (1.f + expf(-s));
    }
}

// ---------------- B' = cw*att -> f16 hi/lo MFMA B-fragments (K=1280, N=128) ----
// slot g = (nt*40 + ks)*64 + kg*16 + rc ; col=nt*16+rc, k=ks*32+kg*8+e.
// (k0..k0+7 share one layer since k0 % 8 == 0 and layer stride 256.)
__global__ void k_bprime(const float* __restrict__ cw, const float* __restrict__ att,
                         ushort* __restrict__ bph, ushort* __restrict__ bpl) {
    int g = blockIdx.x * blockDim.x + threadIdx.x;
    if (g >= 20480) return;                       // 8 nt * 40 ks * 64 lanes
    int rc = g & 15, kg = (g >> 4) & 3, rest = g >> 6;
    int ks = rest % 40, nt = rest / 40;
    int col = nt * 16 + rc, k0 = ks * 32 + kg * 8;
    const float* src = cw + (size_t)col * (NLAYERS * FEAT) + k0;
    float a = att[k0 >> 8];
    uint hw[4], lw[4];
#pragma unroll
    for (int e = 0; e < 8; e += 2) {
        ushort h0, l0, h1, l1;
        f16split(src[e] * a, h0, l0);
        f16split(src[e + 1] * a, h1, l1);
        hw[e >> 1] = (uint)h0 | ((uint)h1 << 16);
        lw[e >> 1] = (uint)l0 | ((uint)l1 << 16);
    }
    size_t dst = (size_t)g * 8;
    *(uint4*)(bph + dst) = make_uint4(hw[0], hw[1], hw[2], hw[3]);
    *(uint4*)(bpl + dst) = make_uint4(lw[0], lw[1], lw[2], lw[3]);
}

// ---------------- split-f16 pack for the final MFMA GEMM ----------------------
// src[row][k] fp32 (10000x128) -> hi/lo f16 fragment-native; rows>=10000 zeroed.
__global__ __launch_bounds__(256) void k_pack(const float* __restrict__ src,
        ushort* __restrict__ hi, ushort* __restrict__ lo) {
    int t = blockIdx.x * blockDim.x + threadIdx.x;     // 10112*16 = 161792 threads
    int row = t >> 4;
    int g = t & 15;                                    // which group of 8 k's
    int mt = row >> 4, rr = row & 15;
    int ks = g >> 2, kg = g & 3;
    size_t dst = ((size_t)(mt * 4 + ks) * 64 + kg * 16 + rr) * 8;
    uint h[4] = {0, 0, 0, 0}, l[4] = {0, 0, 0, 0};
    if (row < N_NODES) {
        const float* p = src + (size_t)row * NOC + g * 8;
#pragma unroll
        for (int e = 0; e < 8; ++e) {
            ushort hu, lu;
            f16split(p[e], hu, lu);
            h[e >> 1] |= (uint)hu << ((e & 1) * 16);
            l[e >> 1] |= (uint)lu << ((e & 1) * 16);
        }
    }
    *(uint4*)(hi + dst) = make_uint4(h[0], h[1], h[2], h[3]);
    *(uint4*)(lo + dst) = make_uint4(l[0], l[1], l[2], l[3]);
}

// ---------------- final C[10000,10000] = X @ Y^T via split-f16 MFMA -----------
__global__ __launch_bounds__(256) void k_final_mfma(
        const ushort* __restrict__ xh, const ushort* __restrict__ xl,
        const ushort* __restrict__ yh, const ushort* __restrict__ yl,
        float* __restrict__ C) {
    // bijective XCD swizzle (nwg = 6241 = 8*780 + 1)
    int bid = blockIdx.x;
    const int nwg = NTILE * NTILE;
    const int q = nwg >> 3, r = nwg & 7;
    int xcd = bid & 7, loc = bid >> 3;
    int wg = (xcd < r ? xcd * (q + 1) : r * (q + 1) + (xcd - r) * q) + loc;
    int tm = wg / NTILE, tn = wg % NTILE;

    int tid = threadIdx.x;
    int wave = tid >> 6, lane = tid & 63;
    int m0 = tm * 128 + (wave >> 1) * 64;
    int n0 = tn * 128 + (wave & 1) * 64;
    int mtb = m0 >> 4, ntb = n0 >> 4;

    f32x4 acc[4][4];
#pragma unroll
    for (int i = 0; i < 4; ++i)
#pragma unroll
        for (int j = 0; j < 4; ++j) acc[i][j] = (f32x4){0.f, 0.f, 0.f, 0.f};

#pragma unroll
    for (int ks = 0; ks < 4; ++ks) {
        f16x8 ah[4], al[4], bh[4], bl[4];
#pragma unroll
        for (int i = 0; i < 4; ++i) {
            size_t ao = ((size_t)((mtb + i) * 4 + ks) * 64 + lane) * 8;
            size_t bo = ((size_t)((ntb + i) * 4 + ks) * 64 + lane) * 8;
            ah[i] = *(const f16x8*)(xh + ao);
            al[i] = *(const f16x8*)(xl + ao);
            bh[i] = *(const f16x8*)(yh + bo);
            bl[i] = *(const f16x8*)(yl + bo);
        }
#pragma unroll
        for (int i = 0; i < 4; ++i)
#pragma unroll
            for (int j = 0; j < 4; ++j) {
                acc[i][j] = __builtin_amdgcn_mfma_f32_16x16x32_f16(ah[i], bh[j], acc[i][j], 0, 0, 0);
                acc[i][j] = __builtin_amdgcn_mfma_f32_16x16x32_f16(ah[i], bl[j], acc[i][j], 0, 0, 0);
                acc[i][j] = __builtin_amdgcn_mfma_f32_16x16x32_f16(al[i], bh[j], acc[i][j], 0, 0, 0);
            }
    }

    // D frag layout: row = (lane>>4)*4 + reg, col = lane&15
    int rbase = (lane >> 4) * 4, cn = lane & 15;
    bool full = (m0 + 63 < N_NODES) && (n0 + 63 < N_NODES);
    if (full) {
#pragma unroll
        for (int i = 0; i < 4; ++i)
#pragma unroll
            for (int j = 0; j < 4; ++j) {
                size_t base = (size_t)(m0 + i * 16 + rbase) * N_NODES + (n0 + j * 16 + cn);
#pragma unroll
                for (int rr = 0; rr < 4; ++rr)
                    C[base + (size_t)rr * N_NODES] = acc[i][j][rr];
            }
    } else {
        for (int i = 0; i < 4; ++i)
            for (int j = 0; j < 4; ++j) {
                int ccol = n0 + j * 16 + cn;
                if (ccol >= N_NODES) continue;
                for (int rr = 0; rr < 4; ++rr) {
                    int mr = m0 + i * 16 + rbase + rr;
                    if (mr < N_NODES)
                        C[(size_t)mr * N_NODES + ccol] = acc[i][j][rr];
                }
            }
    }
}

extern "C" void kernel_launch(void* const* d_in, const int* in_sizes, int n_in,
                              void* d_out, int out_size, void* d_ws, size_t ws_size,
                              hipStream_t stream) {
    (void)in_sizes; (void)n_in; (void)out_size; (void)ws_size;

    // ---- workspace carve-up (identical footprint to verified round-17 layout) ----
    float* ws     = (float*)d_ws;
    float* feats  = ws;                          // 5*10000*256 = 12,800,000
    float* tbuf   = feats + 12800000;            // 2,560,000 (holds th/tl packed)
    float* outx   = tbuf + 2560000;              // 1,280,000
    float* outy   = outx + 1280000;              // 1,280,000
    float* dinv   = outy + 1280000;              // 10,016
    float* val    = dinv + 10016;                // 320,000
    float* bprime = val + 320000;                // 163,840 (now f16 hi/lo B-frags)
    float* attF   = bprime + 163840;             // 16
    int*   ptr    = (int*)(attF + 16);           // 10,016
    int*   cnt    = ptr + 10016;                 // 10,016
    int*   fill   = cnt + 10016;                 // 10,016
    int*   col    = fill + 10016;                // 320,000
    int*   attm   = col + 320000;                // 16

    // packed f16 t (A-side, per layer): exactly fills tbuf (2*2.56M ushorts)
    ushort* th = (ushort*)tbuf;
    ushort* tl = th + 2560000;
    // packed f16 W (B-side, 5 layers): aliases outy (outy written only at branch-1
    // end, after the last layer GEMM of branch 1 -> no overlap in lifetime)
    ushort* Wh = (ushort*)outy;
    ushort* Wl = Wh + NLAYERS * 65536;           // 2*327,680 ushorts = 327,680 floats

    // packed f16 B' (branch-out): exactly fills the bprime region
    ushort* bph = (ushort*)bprime;               // 163,840 ushorts
    ushort* bpl = bph + 163840;                  // 163,840 ushorts = 163,840 floats tot

    // final-GEMM packed operands alias feats (dead after branch-out GEMMs)
    ushort* pxh = (ushort*)feats;
    ushort* pxl = pxh + PACKSZ;
    ushort* pyh = pxl + PACKSZ;
    ushort* pyl = pyh + PACKSZ;

    for (int b = 0; b < 2; ++b) {
        const float* x0   = (const float*)d_in[b == 0 ? 0 : 1];
        const float* ew   = (const float*)d_in[b == 0 ? 2 : 3];
        const float* W    = (const float*)d_in[b == 0 ? 4 : 6];
        const float* bias = (const float*)d_in[b == 0 ? 5 : 7];
        const float* fc1w = (const float*)d_in[b == 0 ? 8 : 12];
        const float* fc1b = (const float*)d_in[b == 0 ? 9 : 13];
        const float* fc2w = (const float*)d_in[b == 0 ? 10 : 14];
        const float* fc2b = (const float*)d_in[b == 0 ? 11 : 15];
        const float* cw   = (const float*)d_in[b == 0 ? 16 : 18];
        const float* cb   = (const float*)d_in[b == 0 ? 17 : 19];
        const int* edges  = (const int*)d_in[b == 0 ? 20 : 21];
        float* outb = (b == 0) ? outx : outy;

        k_init<<<40, 256, 0, stream>>>(dinv, cnt, fill, attm);
        k_count<<<1250, 256, 0, stream>>>(edges, ew, dinv, cnt);
        k_dinv<<<40, 256, 0, stream>>>(dinv);
        k_scan<<<1, 1024, 0, stream>>>(cnt, ptr);
        k_fill<<<1250, 256, 0, stream>>>(edges, ew, dinv, ptr, fill, col, val);
        k_packW<<<160, 256, 0, stream>>>(W, Wh, Wl);

        for (int l = 0; l < NLAYERS; ++l) {
            const float* prev = (l == 0) ? x0 : (feats + (size_t)(l - 1) * N_NODES * FEAT);
            k_spmm<<<2500, 256, 0, stream>>>(prev, ptr, col, val, dinv, th, tl);
            k_gemm_l<<<dim3(79, 2), 256, 0, stream>>>(
                th, tl, Wh + (size_t)l * 65536, Wl + (size_t)l * 65536,
                bias + (size_t)l * FEAT,
                feats + (size_t)l * N_NODES * FEAT, attm + l);
        }

        k_att<<<1, 64, 0, stream>>>(attm, fc1w, fc1b, fc2w, fc2b, attF);
        k_bprime<<<80, 256, 0, stream>>>(cw, attF, bph, bpl);
        k_gemm_out<<<157, 256, 0, stream>>>(feats, bph, bpl, cb, outb);
    }

    // pack outx/outy into fragment-native split-f16 (feats now dead -> aliased)
    k_pack<<<632, 256, 0, stream>>>(outx, pxh, pxl);
    k_pack<<<632, 256, 0, stream>>>(outy, pyh, pyl);
    k_final_mfma<<<NTILE * NTILE, 256, 0, stream>>>(pxh, pxl, pyh, pyl, (float*)d_out);
}